// Round 9
// baseline (288.800 us; speedup 1.0000x reference)
//
#include <hip/hip_runtime.h>
#include <math.h>

#ifndef M_PI
#define M_PI 3.14159265358979323846
#endif

typedef _Float16 f16;
typedef _Float16 f16x8 __attribute__((ext_vector_type(8)));
typedef unsigned short u16x8 __attribute__((ext_vector_type(8)));
typedef float f32x4 __attribute__((ext_vector_type(4)));

#define NPHI 511
#define NM   255

// ---------------- K_leg: GL nodes + legh + leghT + w64 ----------------------
// Tricomi init + 2 Newton sweeps; all LDS-table reads group-prefetched so the
// ~120cy LDS latency hides under the serial fp64 chain (was 42.7us chain-bound).
__global__ __launch_bounds__(256) void k_leg(f16* __restrict__ legh, f16* __restrict__ leghT,
                                             double* __restrict__ w64) {
    __shared__ double rtab[258];    // rtab[k] = 1/k, k=2..257
    __shared__ double2 sab[136];    // sab[l] = (sa[l], sb[l]) per-block (depends on m)
    __shared__ double lg[256];
    int m = blockIdx.x, t = threadIdx.x;
    // 1/k table
    if (t >= 2) rtab[t] = 1.0 / (double)t;
    if (t < 2)  rtab[256 + t] = 1.0 / (double)(256 + t);
    // sa/sb table (NaN for l<m is fine: guarded by select below)
    if (t < 136) {
        double a = 1.0, b = 0.0;
        if (t >= 2 && t < 128) {
            double dl = t, dm = m;
            a = sqrt((4.0 * dl * dl - 1.0) / (dl * dl - dm * dm));
            b = sqrt(((dl - 1.0) * (dl - 1.0) - dm * dm) / (4.0 * (dl - 1.0) * (dl - 1.0) - 1.0));
        }
        sab[t].x = a; sab[t].y = b;
    }
    // log-terms for pmm prefix product: sum_{k=1..m} 0.5*log((2k+1)/(2k))
    lg[t] = (t >= 1 && t <= m) ? 0.5 * log1p(0.5 / (double)t) : 0.0;
    __syncthreads();
    for (int s = 128; s > 0; s >>= 1) {
        if (t < s) lg[t] += lg[t + s];
        __syncthreads();
    }
    double sumlog = lg[0];

    // Tricomi initial guess (err ~1e-6 worst-case at endpoints)
    const int n = 256;
    double theta = M_PI * (t + 0.75) / (n + 0.5);
    double st = sin(theta), ctt = cos(theta);
    double dn = (double)n;
    double x = (1.0 - (dn - 1.0) / (8.0 * dn * dn * dn)
                    - (39.0 - 28.0 / (st * st)) / (384.0 * dn * dn * dn * dn)) * ctt;
    double p1 = x, pd = 1.0;
    for (int it = 0; it < 2; ++it) {
        double p0 = 1.0; p1 = x;
        double rg_[8], rn_[8];
        #pragma unroll
        for (int j = 0; j < 8; ++j) rg_[j] = rtab[2 + j];
        for (int g = 0; g < 31; ++g) {
            #pragma unroll
            for (int j = 0; j < 8; ++j) rn_[j] = rtab[10 + g * 8 + j];
            #pragma unroll
            for (int j = 0; j < 8; ++j) {
                double rk = rg_[j];
                double c1x = (2.0 - rk) * x;     // off critical path
                double c2p = (1.0 - rk) * p0;
                double pk = c1x * p1 - c2p;
                p0 = p1; p1 = pk;
            }
            #pragma unroll
            for (int j = 0; j < 8; ++j) rg_[j] = rn_[j];
        }
        // tail k=250..256 (rg_ holds coefficients for k=250..257)
        #pragma unroll
        for (int j = 0; j < 7; ++j) {
            double rk = rg_[j];
            double c1x = (2.0 - rk) * x;
            double c2p = (1.0 - rk) * p0;
            double pk = c1x * p1 - c2p;
            p0 = p1; p1 = pk;
        }
        pd = dn * (x * p1 - p0) / (x * x - 1.0);
        x -= p1 / pd;   // final iter: stale pd err <=1e-8 interior (weight impact nil)
    }
    if (m == 0) w64[t] = 2.0 / ((1.0 - x * x) * pd * pd);

    // pmm = 1/sqrt(4pi) * (-1)^m * exp(sumlog) * sx^m   (binary pow, 7 steps)
    double sx = sqrt(fmax(0.0, 1.0 - x * x));
    double prodm = exp(sumlog);
    if (m & 1) prodm = -prodm;
    double sxm = 1.0, bse = sx;
    int e = m;
    #pragma unroll
    for (int b7 = 0; b7 < 7; ++b7) { if (e & 1) sxm *= bse; bse *= bse; e >>= 1; }
    double pmm = 0.28209479177387814 * prodm * sxm;
    double pm1 = (m + 1 < 128) ? sqrt(2.0 * m + 3.0) * x * pmm : 0.0;

    // l-recurrence with 8-ahead sab prefetch + batched LmT stores
    f16* Lm  = legh  + (size_t)m * 32768;
    f16* LmT = leghT + (size_t)m * 32768;
    double pprev = 0.0, pcur = 0.0;
    double2 cg[8], ng[8];
    #pragma unroll
    for (int j = 0; j < 8; ++j) cg[j] = sab[j];
    for (int g = 0; g < 16; ++g) {
        #pragma unroll
        for (int j = 0; j < 8; ++j) ng[j] = sab[(g + 1) * 8 + j];
        __align__(16) f16 tbuf[8];
        #pragma unroll
        for (int j = 0; j < 8; ++j) {
            int l = g * 8 + j;
            double v;
            if (l < m) v = 0.0;
            else if (l == m) v = pmm;
            else if (l == m + 1) v = pm1;
            else v = cg[j].x * (x * pcur - cg[j].y * pprev);
            if (l >= m) { pprev = pcur; pcur = v; }
            f16 h = (f16)v;
            Lm[l * 256 + t] = h;
            tbuf[j] = h;
        }
        *(float4*)(LmT + (size_t)t * 128 + g * 8) = *(float4*)tbuf;
        #pragma unroll
        for (int j = 0; j < 8; ++j) cg[j] = ng[j];
    }
}

// ---------------- K_tables: CS[2][128][512] (cos*s | -sin*s), A5[512][512] --
// A5 columns k=510,511 are EXACTLY ZERO -> G pad rows need no zeroing.
__global__ void k_tables_h(f16* __restrict__ CS, f16* __restrict__ A5) {
    int tid = blockIdx.x * blockDim.x + threadIdx.x;
    const float w0 = (float)(2.0 * M_PI / 511.0);
    if (tid < 128 * 512) {
        int m = tid >> 9, p = tid & 511;
        float cv = 0.f, sv = 0.f;
        if (p < 511) {
            int r = (p * m) % 511;
            float ang = w0 * (float)r;
            cv = cosf(ang) * w0;
            sv = -sinf(ang) * w0;
        }
        CS[tid] = (f16)cv; CS[65536 + tid] = (f16)sv;
    }
    {
        int p = tid >> 9, k = tid & 511;
        float v = 0.f;
        if (p < 511 && k < 510) {
            int mp = k >> 1, mmv = mp - 127;
            int r = (p * mmv) % 511; if (r < 0) r += 511;
            float ang = w0 * (float)r;
            v = (k & 1) ? -sinf(ang) : cosf(ang);
        }
        A5[tid] = (f16)v;
    }
}

// ---------------- K_prep_R: phi(l) reduce + Rph[l][co][ci] = R*phi ----------
__global__ __launch_bounds__(256) void k_prep_R(const float* __restrict__ Rr, const float* __restrict__ Ri,
        const float* __restrict__ Ar, const float* __restrict__ Ai, const float* __restrict__ te,
        f16* __restrict__ Rphr, f16* __restrict__ Rphi) {
    __shared__ float srd[256], sid[256];
    int l = blockIdx.x, tid = threadIdx.x;
    float tv = te[tid];
    srd[tid] = Ar[l * 256 + tid] * tv;
    sid[tid] = Ai[l * 256 + tid] * tv;
    __syncthreads();
    for (int s = 128; s > 0; s >>= 1) {
        if (tid < s) { srd[tid] += srd[tid + s]; sid[tid] += sid[tid + s]; }
        __syncthreads();
    }
    float phr = srd[0], phii = sid[0];
    const float* rr = Rr + (size_t)l * 4096;
    const float* ri = Ri + (size_t)l * 4096;
    #pragma unroll
    for (int e = 0; e < 2; ++e) {
        int base = tid * 8 + e * 2048;
        float4 r0 = *(const float4*)(rr + base), r1 = *(const float4*)(rr + base + 4);
        float4 q0 = *(const float4*)(ri + base), q1 = *(const float4*)(ri + base + 4);
        __align__(16) f16 hr[8], hi[8];
        hr[0] = (f16)(r0.x * phr - q0.x * phii); hi[0] = (f16)(r0.x * phii + q0.x * phr);
        hr[1] = (f16)(r0.y * phr - q0.y * phii); hi[1] = (f16)(r0.y * phii + q0.y * phr);
        hr[2] = (f16)(r0.z * phr - q0.z * phii); hi[2] = (f16)(r0.z * phii + q0.z * phr);
        hr[3] = (f16)(r0.w * phr - q0.w * phii); hi[3] = (f16)(r0.w * phii + q0.w * phr);
        hr[4] = (f16)(r1.x * phr - q1.x * phii); hi[4] = (f16)(r1.x * phii + q1.x * phr);
        hr[5] = (f16)(r1.y * phr - q1.y * phii); hi[5] = (f16)(r1.y * phii + q1.y * phr);
        hr[6] = (f16)(r1.z * phr - q1.z * phii); hi[6] = (f16)(r1.z * phii + q1.z * phr);
        hr[7] = (f16)(r1.w * phr - q1.w * phii); hi[7] = (f16)(r1.w * phii + q1.w * phr);
        *(float4*)(Rphr + (size_t)l * 4096 + base) = *(float4*)hr;
        *(float4*)(Rphi + (size_t)l * 4096 + base) = *(float4*)hi;
    }
}

// ---------------- K_convert: x[t][p][c] f32 -> xh[t][c][p(512)] f16 ---------
__global__ __launch_bounds__(256) void k_convert(const float* __restrict__ x, f16* __restrict__ xh) {
    __shared__ float Ls[64][68];
    int t = blockIdx.x, pt = blockIdx.y, tid = threadIdx.x;
    int p0 = pt * 64;
    const float* xb = x + (size_t)t * (NPHI * 64);
    #pragma unroll
    for (int e = 0; e < 4; ++e) {
        int idx = tid + e * 256;
        int row = idx >> 4, c4 = (idx & 15) * 4;
        int p = p0 + row;
        float4 v = make_float4(0.f, 0.f, 0.f, 0.f);
        if (p < NPHI) v = *(const float4*)(xb + (size_t)p * 64 + c4);
        *(float4*)&Ls[row][c4] = v;
    }
    __syncthreads();
    #pragma unroll
    for (int e = 0; e < 2; ++e) {
        int idx = tid + e * 256;
        int c = idx >> 3, r8 = (idx & 7) * 8;
        __align__(16) f16 tmp[8];
        #pragma unroll
        for (int j = 0; j < 8; ++j) tmp[j] = (f16)Ls[r8 + j][c];
        *(float4*)(xh + (size_t)t * 32768 + (size_t)c * 512 + p0 + r8) = *(float4*)tmp;
    }
}

// ---------------- generic fp16 transpose tile body --------------------------
__device__ __forceinline__ void tr16_body(const f16* __restrict__ s, f16* __restrict__ d,
                                          int R, int C, int rt, int ct, int tid) {
    __shared__ f16 Ts[64][72];
    const f16* sp = s + (size_t)(rt * 64) * C + ct * 64;
    #pragma unroll
    for (int e = 0; e < 2; ++e) {
        int idx = tid + e * 256;
        int row = idx >> 3, c8 = (idx & 7) * 8;
        *(float4*)&Ts[row][c8] = *(const float4*)(sp + (size_t)row * C + c8);
    }
    __syncthreads();
    f16* dp = d + (size_t)(ct * 64) * R + rt * 64;
    #pragma unroll
    for (int e = 0; e < 2; ++e) {
        int idx = tid + e * 256;
        int c = idx >> 3, r8 = (idx & 7) * 8;
        __align__(16) f16 tmp[8];
        #pragma unroll
        for (int j = 0; j < 8; ++j) tmp[j] = Ts[r8 + j][c];
        *(float4*)(dp + (size_t)c * R + r8) = *(float4*)tmp;
    }
}

__global__ __launch_bounds__(256) void k_tr16(const f16* __restrict__ src, f16* __restrict__ dst,
                                              int R, int C) {
    int b = blockIdx.x, tile = blockIdx.y, tid = threadIdx.x;
    int ctiles = C >> 6;
    int rt = tile / ctiles, ct = tile - rt * ctiles;
    tr16_body(src + (size_t)b * R * C, dst + (size_t)b * R * C, R, C, rt, ct, tid);
}

__global__ __launch_bounds__(256) void k_trp(const f16* __restrict__ s0, f16* __restrict__ d0,
                                             const f16* __restrict__ s1, f16* __restrict__ d1,
                                             int R, int C, int sstr, int dstr) {
    int b = blockIdx.x, tile = blockIdx.y, tid = threadIdx.x;
    int ctiles = C >> 6;
    int rt = tile / ctiles, ct = tile - rt * ctiles;
    const f16* s = ((blockIdx.z == 0) ? s0 : s1) + (size_t)b * sstr;
    f16*       d = ((blockIdx.z == 0) ? d0 : d1) + (size_t)b * dstr;
    tr16_body(s, d, R, C, rt, ct, tid);
}

// ---------------- K_g1: stage 1 MFMA (64-tile, round-4 form) ----------------
__global__ __launch_bounds__(256) void k_g1(const f16* __restrict__ xh, const f16* __restrict__ cF,
        const f16* __restrict__ sF, const double* __restrict__ w64,
        f16* __restrict__ FwR, f16* __restrict__ FwI) {
    __shared__ f16 Ac[64][40], An[64][40], Bs[64][40];
    int t = blockIdx.x, mt = blockIdx.y, tid = threadIdx.x;
    const f16* A0 = cF + (size_t)(mt * 64) * 512;
    const f16* A1 = sF + (size_t)(mt * 64) * 512;
    const f16* B  = xh + (size_t)t * (64 * 512);
    f32x4 acc[2][2][2];  // [tab][mf][nf]
    #pragma unroll
    for (int a = 0; a < 2; ++a)
        #pragma unroll
        for (int b = 0; b < 2; ++b)
            #pragma unroll
            for (int c = 0; c < 2; ++c) acc[a][b][c] = (f32x4){0.f, 0.f, 0.f, 0.f};
    int lane = tid & 63, wid = tid >> 6;
    int wm = wid & 1, wn = wid >> 1;
    int fr = lane & 15, g8 = (lane >> 4) * 8;
    int row = tid >> 2, k8 = (tid & 3) * 8;
    for (int kt = 0; kt < 16; ++kt) {
        float4 va = *(const float4*)(A0 + (size_t)row * 512 + kt * 32 + k8);
        float4 vn = *(const float4*)(A1 + (size_t)row * 512 + kt * 32 + k8);
        float4 vb = *(const float4*)(B  + (size_t)row * 512 + kt * 32 + k8);
        __syncthreads();
        *(float4*)&Ac[row][k8] = va;
        *(float4*)&An[row][k8] = vn;
        *(float4*)&Bs[row][k8] = vb;
        __syncthreads();
        f16x8 b0 = *(f16x8*)&Bs[wn * 32 + fr][g8];
        f16x8 b1 = *(f16x8*)&Bs[wn * 32 + 16 + fr][g8];
        f16x8 a0 = *(f16x8*)&Ac[wm * 32 + fr][g8];
        f16x8 a1 = *(f16x8*)&Ac[wm * 32 + 16 + fr][g8];
        f16x8 s0 = *(f16x8*)&An[wm * 32 + fr][g8];
        f16x8 s1 = *(f16x8*)&An[wm * 32 + 16 + fr][g8];
        acc[0][0][0] = __builtin_amdgcn_mfma_f32_16x16x32_f16(a0, b0, acc[0][0][0], 0, 0, 0);
        acc[0][0][1] = __builtin_amdgcn_mfma_f32_16x16x32_f16(a0, b1, acc[0][0][1], 0, 0, 0);
        acc[0][1][0] = __builtin_amdgcn_mfma_f32_16x16x32_f16(a1, b0, acc[0][1][0], 0, 0, 0);
        acc[0][1][1] = __builtin_amdgcn_mfma_f32_16x16x32_f16(a1, b1, acc[0][1][1], 0, 0, 0);
        acc[1][0][0] = __builtin_amdgcn_mfma_f32_16x16x32_f16(s0, b0, acc[1][0][0], 0, 0, 0);
        acc[1][0][1] = __builtin_amdgcn_mfma_f32_16x16x32_f16(s0, b1, acc[1][0][1], 0, 0, 0);
        acc[1][1][0] = __builtin_amdgcn_mfma_f32_16x16x32_f16(s1, b0, acc[1][1][0], 0, 0, 0);
        acc[1][1][1] = __builtin_amdgcn_mfma_f32_16x16x32_f16(s1, b1, acc[1][1][1], 0, 0, 0);
    }
    float wf = (float)w64[t];
    int rg = (lane >> 4) * 4;
    #pragma unroll
    for (int mf = 0; mf < 2; ++mf)
        #pragma unroll
        for (int nf = 0; nf < 2; ++nf) {
            int c = wn * 32 + nf * 16 + fr;
            #pragma unroll
            for (int r = 0; r < 4; ++r) {
                int m = mt * 64 + wm * 32 + mf * 16 + rg + r;
                FwR[((size_t)m * 256 + t) * 64 + c] = (f16)(acc[0][mf][nf][r] * wf);
                FwI[((size_t)m * 256 + t) * 64 + c] = (f16)(acc[1][mf][nf][r] * wf);
            }
        }
}

// ---------------- K_g2: stage 2 MFMA (64-tile, round-4 form) ----------------
__global__ __launch_bounds__(256) void k_g2(const f16* __restrict__ legh, const f16* __restrict__ BTr,
        const f16* __restrict__ BTi, f16* __restrict__ Xhr, f16* __restrict__ Xhi) {
    __shared__ f16 As[64][40], Br[64][40], Bi[64][40];
    int m = blockIdx.x, lt = blockIdx.y, tid = threadIdx.x;
    const f16* A  = legh + (size_t)m * (128 * 256) + (size_t)(lt * 64) * 256;
    const f16* B0 = BTr + (size_t)m * (64 * 256);
    const f16* B1 = BTi + (size_t)m * (64 * 256);
    f32x4 acc[2][2][2];  // [bsel][mf][nf]
    #pragma unroll
    for (int a = 0; a < 2; ++a)
        #pragma unroll
        for (int b = 0; b < 2; ++b)
            #pragma unroll
            for (int c = 0; c < 2; ++c) acc[a][b][c] = (f32x4){0.f, 0.f, 0.f, 0.f};
    int lane = tid & 63, wid = tid >> 6;
    int wm = wid & 1, wn = wid >> 1;
    int fr = lane & 15, g8 = (lane >> 4) * 8;
    int row = tid >> 2, k8 = (tid & 3) * 8;
    for (int kt = 0; kt < 8; ++kt) {
        float4 va = *(const float4*)(A  + (size_t)row * 256 + kt * 32 + k8);
        float4 vr = *(const float4*)(B0 + (size_t)row * 256 + kt * 32 + k8);
        float4 vi = *(const float4*)(B1 + (size_t)row * 256 + kt * 32 + k8);
        __syncthreads();
        *(float4*)&As[row][k8] = va;
        *(float4*)&Br[row][k8] = vr;
        *(float4*)&Bi[row][k8] = vi;
        __syncthreads();
        f16x8 a0 = *(f16x8*)&As[wm * 32 + fr][g8];
        f16x8 a1 = *(f16x8*)&As[wm * 32 + 16 + fr][g8];
        f16x8 r0 = *(f16x8*)&Br[wn * 32 + fr][g8];
        f16x8 r1 = *(f16x8*)&Br[wn * 32 + 16 + fr][g8];
        f16x8 i0 = *(f16x8*)&Bi[wn * 32 + fr][g8];
        f16x8 i1 = *(f16x8*)&Bi[wn * 32 + 16 + fr][g8];
        acc[0][0][0] = __builtin_amdgcn_mfma_f32_16x16x32_f16(a0, r0, acc[0][0][0], 0, 0, 0);
        acc[0][0][1] = __builtin_amdgcn_mfma_f32_16x16x32_f16(a0, r1, acc[0][0][1], 0, 0, 0);
        acc[0][1][0] = __builtin_amdgcn_mfma_f32_16x16x32_f16(a1, r0, acc[0][1][0], 0, 0, 0);
        acc[0][1][1] = __builtin_amdgcn_mfma_f32_16x16x32_f16(a1, r1, acc[0][1][1], 0, 0, 0);
        acc[1][0][0] = __builtin_amdgcn_mfma_f32_16x16x32_f16(a0, i0, acc[1][0][0], 0, 0, 0);
        acc[1][0][1] = __builtin_amdgcn_mfma_f32_16x16x32_f16(a0, i1, acc[1][0][1], 0, 0, 0);
        acc[1][1][0] = __builtin_amdgcn_mfma_f32_16x16x32_f16(a1, i0, acc[1][1][0], 0, 0, 0);
        acc[1][1][1] = __builtin_amdgcn_mfma_f32_16x16x32_f16(a1, i1, acc[1][1][1], 0, 0, 0);
    }
    int rg = (lane >> 4) * 4;
    #pragma unroll
    for (int mf = 0; mf < 2; ++mf)
        #pragma unroll
        for (int nf = 0; nf < 2; ++nf) {
            int c = wn * 32 + nf * 16 + fr;
            #pragma unroll
            for (int r = 0; r < 4; ++r) {
                int l = lt * 64 + wm * 32 + mf * 16 + rg + r;
                Xhr[(size_t)m * 8192 + l * 64 + c] = (f16)acc[0][mf][nf][r];
                Xhi[(size_t)m * 8192 + l * 64 + c] = (f16)acc[1][mf][nf][r];
            }
        }
}

// ---------------- K_s3m: stage 3 MFMA (round-4 form) ------------------------
__global__ __launch_bounds__(256) void k_s3m(const f16* __restrict__ Xhr, const f16* __restrict__ Xhi,
        const f16* __restrict__ Rphr, const f16* __restrict__ Rphi,
        f16* __restrict__ Or, f16* __restrict__ Oi) {
    __shared__ f16 Ars[64][72], Ais[64][72], Ans[64][72];
    int l = blockIdx.x, mt = blockIdx.y, tid = threadIdx.x;
    {
        int arow = tid >> 2;
        int mp = mt * 64 + arow;
        int mmv = mp - 127, am = mmv < 0 ? -mmv : mmv;
        unsigned short cj = (mmv < 0) ? 0x8000 : 0;
        u16x8 cjv = {cj, cj, cj, cj, cj, cj, cj, cj};
        u16x8 ngv = {0x8000, 0x8000, 0x8000, 0x8000, 0x8000, 0x8000, 0x8000, 0x8000};
        #pragma unroll
        for (int e = 0; e < 2; ++e) {
            int ci8 = (tid & 3) * 8 + e * 32;
            u16x8 vr = {0, 0, 0, 0, 0, 0, 0, 0};
            u16x8 vi = {0, 0, 0, 0, 0, 0, 0, 0};
            if (mp < 255) {
                vr = *(const u16x8*)(Xhr + (size_t)am * 8192 + l * 64 + ci8);
                vi = *(const u16x8*)(Xhi + (size_t)am * 8192 + l * 64 + ci8);
            }
            u16x8 vic = vi ^ cjv;
            u16x8 vin = vic ^ ngv;
            *(u16x8*)&Ars[arow][ci8] = vr;
            *(u16x8*)&Ais[arow][ci8] = vic;
            *(u16x8*)&Ans[arow][ci8] = vin;
        }
    }
    __syncthreads();
    int lane = tid & 63, wid = tid >> 6;
    int wm = wid & 1, wn = wid >> 1;
    int fr = lane & 15, g8 = (lane >> 4) * 8;
    const f16* Bre = Rphr + (size_t)l * 4096;
    const f16* Bim = Rphi + (size_t)l * 4096;
    f32x4 accr[2][2], acci[2][2];
    #pragma unroll
    for (int a = 0; a < 2; ++a)
        #pragma unroll
        for (int b = 0; b < 2; ++b) { accr[a][b] = (f32x4){0.f,0.f,0.f,0.f}; acci[a][b] = (f32x4){0.f,0.f,0.f,0.f}; }
    #pragma unroll
    for (int ks = 0; ks < 2; ++ks) {
        int ko = ks * 32 + g8;
        f16x8 ar0 = *(f16x8*)&Ars[wm * 32 + fr][ko];
        f16x8 ar1 = *(f16x8*)&Ars[wm * 32 + 16 + fr][ko];
        f16x8 ai0 = *(f16x8*)&Ais[wm * 32 + fr][ko];
        f16x8 ai1 = *(f16x8*)&Ais[wm * 32 + 16 + fr][ko];
        f16x8 an0 = *(f16x8*)&Ans[wm * 32 + fr][ko];
        f16x8 an1 = *(f16x8*)&Ans[wm * 32 + 16 + fr][ko];
        #pragma unroll
        for (int nf = 0; nf < 2; ++nf) {
            int brow = wn * 32 + nf * 16 + fr;
            f16x8 br = *(const f16x8*)(Bre + (size_t)brow * 64 + ko);
            f16x8 bi = *(const f16x8*)(Bim + (size_t)brow * 64 + ko);
            accr[0][nf] = __builtin_amdgcn_mfma_f32_16x16x32_f16(ar0, br, accr[0][nf], 0, 0, 0);
            accr[0][nf] = __builtin_amdgcn_mfma_f32_16x16x32_f16(an0, bi, accr[0][nf], 0, 0, 0);
            acci[0][nf] = __builtin_amdgcn_mfma_f32_16x16x32_f16(ar0, bi, acci[0][nf], 0, 0, 0);
            acci[0][nf] = __builtin_amdgcn_mfma_f32_16x16x32_f16(ai0, br, acci[0][nf], 0, 0, 0);
            accr[1][nf] = __builtin_amdgcn_mfma_f32_16x16x32_f16(ar1, br, accr[1][nf], 0, 0, 0);
            accr[1][nf] = __builtin_amdgcn_mfma_f32_16x16x32_f16(an1, bi, accr[1][nf], 0, 0, 0);
            acci[1][nf] = __builtin_amdgcn_mfma_f32_16x16x32_f16(ar1, bi, acci[1][nf], 0, 0, 0);
            acci[1][nf] = __builtin_amdgcn_mfma_f32_16x16x32_f16(ai1, br, acci[1][nf], 0, 0, 0);
        }
    }
    int rg = (lane >> 4) * 4;
    #pragma unroll
    for (int mf = 0; mf < 2; ++mf)
        #pragma unroll
        for (int nf = 0; nf < 2; ++nf) {
            int co = wn * 32 + nf * 16 + fr;
            #pragma unroll
            for (int r = 0; r < 4; ++r) {
                int mp = mt * 64 + wm * 32 + mf * 16 + rg + r;
                if (mp < 255) {
                    Or[(size_t)mp * 8192 + l * 64 + co] = (f16)accr[mf][nf][r];
                    Oi[(size_t)mp * 8192 + l * 64 + co] = (f16)acci[mf][nf][r];
                }
            }
        }
}

// ---------------- K_g4: stage 4 MFMA (64-tile, round-4 form) ----------------
__global__ __launch_bounds__(256) void k_g4(const f16* __restrict__ legT, const f16* __restrict__ OTr,
        const f16* __restrict__ OTi, f16* __restrict__ G) {
    __shared__ f16 As[64][40], Br[64][40], Bi[64][40];
    int mp = blockIdx.x, tt = blockIdx.y, tid = threadIdx.x;
    int mmv = mp - 127, am = mmv < 0 ? -mmv : mmv;
    const f16* A  = legT + (size_t)am * (256 * 128) + (size_t)(tt * 64) * 128;
    const f16* B0 = OTr + (size_t)mp * (64 * 128);
    const f16* B1 = OTi + (size_t)mp * (64 * 128);
    f32x4 acc[2][2][2];
    #pragma unroll
    for (int a = 0; a < 2; ++a)
        #pragma unroll
        for (int b = 0; b < 2; ++b)
            #pragma unroll
            for (int c = 0; c < 2; ++c) acc[a][b][c] = (f32x4){0.f, 0.f, 0.f, 0.f};
    int lane = tid & 63, wid = tid >> 6;
    int wm = wid & 1, wn = wid >> 1;
    int fr = lane & 15, g8 = (lane >> 4) * 8;
    int row = tid >> 2, k8 = (tid & 3) * 8;
    for (int kt = am >> 5; kt < 4; ++kt) {
        float4 va = *(const float4*)(A  + (size_t)row * 128 + kt * 32 + k8);
        float4 vr = *(const float4*)(B0 + (size_t)row * 128 + kt * 32 + k8);
        float4 vi = *(const float4*)(B1 + (size_t)row * 128 + kt * 32 + k8);
        __syncthreads();
        *(float4*)&As[row][k8] = va;
        *(float4*)&Br[row][k8] = vr;
        *(float4*)&Bi[row][k8] = vi;
        __syncthreads();
        f16x8 a0 = *(f16x8*)&As[wm * 32 + fr][g8];
        f16x8 a1 = *(f16x8*)&As[wm * 32 + 16 + fr][g8];
        f16x8 r0 = *(f16x8*)&Br[wn * 32 + fr][g8];
        f16x8 r1 = *(f16x8*)&Br[wn * 32 + 16 + fr][g8];
        f16x8 i0 = *(f16x8*)&Bi[wn * 32 + fr][g8];
        f16x8 i1 = *(f16x8*)&Bi[wn * 32 + 16 + fr][g8];
        acc[0][0][0] = __builtin_amdgcn_mfma_f32_16x16x32_f16(a0, r0, acc[0][0][0], 0, 0, 0);
        acc[0][0][1] = __builtin_amdgcn_mfma_f32_16x16x32_f16(a0, r1, acc[0][0][1], 0, 0, 0);
        acc[0][1][0] = __builtin_amdgcn_mfma_f32_16x16x32_f16(a1, r0, acc[0][1][0], 0, 0, 0);
        acc[0][1][1] = __builtin_amdgcn_mfma_f32_16x16x32_f16(a1, r1, acc[0][1][1], 0, 0, 0);
        acc[1][0][0] = __builtin_amdgcn_mfma_f32_16x16x32_f16(a0, i0, acc[1][0][0], 0, 0, 0);
        acc[1][0][1] = __builtin_amdgcn_mfma_f32_16x16x32_f16(a0, i1, acc[1][0][1], 0, 0, 0);
        acc[1][1][0] = __builtin_amdgcn_mfma_f32_16x16x32_f16(a1, i0, acc[1][1][0], 0, 0, 0);
        acc[1][1][1] = __builtin_amdgcn_mfma_f32_16x16x32_f16(a1, i1, acc[1][1][1], 0, 0, 0);
    }
    int rg = (lane >> 4) * 4;
    f16* gr = G + (size_t)(2 * mp) * (256 * 64);
    f16* gi = G + (size_t)(2 * mp + 1) * (256 * 64);
    #pragma unroll
    for (int mf = 0; mf < 2; ++mf)
        #pragma unroll
        for (int nf = 0; nf < 2; ++nf) {
            int c = wn * 32 + nf * 16 + fr;
            #pragma unroll
            for (int r = 0; r < 4; ++r) {
                int tl = tt * 64 + wm * 32 + mf * 16 + rg + r;
                gr[(size_t)tl * 64 + c] = (f16)acc[0][mf][nf][r];
                gi[(size_t)tl * 64 + c] = (f16)acc[1][mf][nf][r];
            }
        }
}

// ---------------- K_g5: stage 5 MFMA (64-tile, round-4 form) ----------------
__global__ __launch_bounds__(256) void k_g5(const f16* __restrict__ A5, const f16* __restrict__ GT,
                                            float* __restrict__ out) {
    __shared__ f16 As[64][40], Bs[64][40];
    int t = blockIdx.x, pt = blockIdx.y, tid = threadIdx.x;
    const f16* A = A5 + (size_t)(pt * 64) * 512;
    const f16* B = GT + (size_t)t * (64 * 512);
    f32x4 acc[2][2];
    #pragma unroll
    for (int a = 0; a < 2; ++a)
        #pragma unroll
        for (int b = 0; b < 2; ++b) acc[a][b] = (f32x4){0.f, 0.f, 0.f, 0.f};
    int lane = tid & 63, wid = tid >> 6;
    int wm = wid & 1, wn = wid >> 1;
    int fr = lane & 15, g8 = (lane >> 4) * 8;
    int row = tid >> 2, k8 = (tid & 3) * 8;
    for (int kt = 0; kt < 16; ++kt) {
        float4 va = *(const float4*)(A + (size_t)row * 512 + kt * 32 + k8);
        float4 vb = *(const float4*)(B + (size_t)row * 512 + kt * 32 + k8);
        __syncthreads();
        *(float4*)&As[row][k8] = va;
        *(float4*)&Bs[row][k8] = vb;
        __syncthreads();
        f16x8 a0 = *(f16x8*)&As[wm * 32 + fr][g8];
        f16x8 a1 = *(f16x8*)&As[wm * 32 + 16 + fr][g8];
        f16x8 b0 = *(f16x8*)&Bs[wn * 32 + fr][g8];
        f16x8 b1 = *(f16x8*)&Bs[wn * 32 + 16 + fr][g8];
        acc[0][0] = __builtin_amdgcn_mfma_f32_16x16x32_f16(a0, b0, acc[0][0], 0, 0, 0);
        acc[0][1] = __builtin_amdgcn_mfma_f32_16x16x32_f16(a0, b1, acc[0][1], 0, 0, 0);
        acc[1][0] = __builtin_amdgcn_mfma_f32_16x16x32_f16(a1, b0, acc[1][0], 0, 0, 0);
        acc[1][1] = __builtin_amdgcn_mfma_f32_16x16x32_f16(a1, b1, acc[1][1], 0, 0, 0);
    }
    int rg = (lane >> 4) * 4;
    #pragma unroll
    for (int mf = 0; mf < 2; ++mf)
        #pragma unroll
        for (int nf = 0; nf < 2; ++nf) {
            int c = wn * 32 + nf * 16 + fr;
            #pragma unroll
            for (int r = 0; r < 4; ++r) {
                int p = pt * 64 + wm * 32 + mf * 16 + rg + r;
                if (p < NPHI) out[((size_t)t * NPHI + p) * 64 + c] = acc[mf][nf][r];
            }
        }
}

extern "C" void kernel_launch(void* const* d_in, const int* in_sizes, int n_in,
                              void* d_out, int out_size, void* d_ws, size_t ws_size,
                              hipStream_t stream) {
    const float* x    = (const float*)d_in[0];
    const float* temb = (const float*)d_in[1];
    const float* Ar   = (const float*)d_in[2];
    const float* Ai   = (const float*)d_in[3];
    const float* Rr   = (const float*)d_in[4];
    const float* Ri   = (const float*)d_in[5];
    float* out = (float*)d_out;

    char* ws = (char*)d_ws;
    size_t off = 0;
    auto alloc = [&](size_t bytes) -> void* {
        void* p = ws + off;
        off = (off + bytes + 255) & ~(size_t)255;
        return p;
    };
    double* w64  = (double*)alloc(256 * 8);
    f16* legh   = (f16*)alloc((size_t)128 * 128 * 256 * 2);   // 8.39 MB
    f16* leghT  = (f16*)alloc((size_t)128 * 256 * 128 * 2);   // 8.39 MB
    f16* CS     = (f16*)alloc((size_t)2 * 128 * 512 * 2);     // 256 KB (cF | sF)
    f16* A5     = (f16*)alloc((size_t)512 * 512 * 2);         // 512 KB
    f16* Rphr   = (f16*)alloc((size_t)128 * 64 * 64 * 2);     // 1.05 MB
    f16* Rphi   = (f16*)alloc((size_t)128 * 64 * 64 * 2);
    f16* R1     = (f16*)alloc((size_t)256 * 64 * 512 * 2);    // 16.78 MB: xh -> GT
    f16* R2     = (f16*)alloc((size_t)512 * 256 * 64 * 2);    // 16.78 MB: Fw{R,I,RT,IT} -> Gk
    f16* Xhr    = (f16*)alloc((size_t)128 * 128 * 64 * 2);    // 2.1 MB
    f16* Xhi    = (f16*)alloc((size_t)128 * 128 * 64 * 2);
    f16* Or     = (f16*)alloc((size_t)255 * 128 * 64 * 2);    // 4.18 MB
    f16* Oi     = (f16*)alloc((size_t)255 * 128 * 64 * 2);
    f16* OrT    = (f16*)alloc((size_t)255 * 64 * 128 * 2);
    f16* OiT    = (f16*)alloc((size_t)255 * 64 * 128 * 2);
    if (off > ws_size) return;

    f16* xh   = R1;
    f16* GT   = R1;
    f16* FwR  = R2;
    f16* FwI  = R2 + (size_t)2097152;
    f16* FwRT = R2 + (size_t)4194304;
    f16* FwIT = R2 + (size_t)6291456;
    f16* Gk   = R2;   // rows 510,511 stale-but-finite; A5 cols 510,511 == 0
    f16* cF   = CS;
    f16* sF   = CS + (size_t)65536;

    hipLaunchKernelGGL(k_leg,      dim3(128),        dim3(256), 0, stream, legh, leghT, w64);
    hipLaunchKernelGGL(k_tables_h, dim3(1024),       dim3(256), 0, stream, CS, A5);
    hipLaunchKernelGGL(k_prep_R,   dim3(128),        dim3(256), 0, stream, Rr, Ri, Ar, Ai, temb, Rphr, Rphi);
    hipLaunchKernelGGL(k_convert,  dim3(256, 8),     dim3(256), 0, stream, x, xh);
    hipLaunchKernelGGL(k_g1,       dim3(256, 2),     dim3(256), 0, stream, xh, cF, sF, w64, FwR, FwI);
    hipLaunchKernelGGL(k_trp,      dim3(128, 4, 2),  dim3(256), 0, stream, FwR, FwRT, FwI, FwIT, 256, 64, 16384, 16384);
    hipLaunchKernelGGL(k_g2,       dim3(128, 2),     dim3(256), 0, stream, legh, FwRT, FwIT, Xhr, Xhi);
    hipLaunchKernelGGL(k_s3m,      dim3(128, 4),     dim3(256), 0, stream, Xhr, Xhi, Rphr, Rphi, Or, Oi);
    hipLaunchKernelGGL(k_trp,      dim3(255, 2, 2),  dim3(256), 0, stream, Or, OrT, Oi, OiT, 128, 64, 8192, 8192);
    hipLaunchKernelGGL(k_g4,       dim3(255, 4),     dim3(256), 0, stream, leghT, OrT, OiT, Gk);
    hipLaunchKernelGGL(k_tr16,     dim3(1, 2048),    dim3(256), 0, stream, Gk, GT, 512, 16384);
    hipLaunchKernelGGL(k_g5,       dim3(256, 8),     dim3(256), 0, stream, A5, GT, out);
}

// Round 10
// 146.429 us; speedup vs baseline: 1.9723x; 1.9723x over previous
//
#include <hip/hip_runtime.h>
#include <math.h>

#ifndef M_PI
#define M_PI 3.14159265358979323846
#endif

typedef _Float16 f16;
typedef _Float16 f16x8 __attribute__((ext_vector_type(8)));
typedef unsigned short u16x8 __attribute__((ext_vector_type(8)));
typedef float f32x4 __attribute__((ext_vector_type(4)));

#define NPHI 511
#define NM   255

// ---------------- K_leg: GL nodes + legh + leghT + w64 ----------------------
// Tricomi init + 2 Newton sweeps with IN-REGISTER coefficients (1/k via fp64
// div, off the p-chain). No large register arrays (round-9 spilled at 256 VGPR).
__global__ __launch_bounds__(256) void k_leg(f16* __restrict__ legh, f16* __restrict__ leghT,
                                             double* __restrict__ w64) {
    __shared__ double sa_[128], sb_[128];
    __shared__ double lg[256];
    int m = blockIdx.x, t = threadIdx.x;
    if (t < 128) {
        double a = 1.0, b = 0.0;
        if (t >= 2) {
            double dl = t, dm = m;
            a = sqrt((4.0 * dl * dl - 1.0) / (dl * dl - dm * dm));
            b = sqrt(((dl - 1.0) * (dl - 1.0) - dm * dm) / (4.0 * (dl - 1.0) * (dl - 1.0) - 1.0));
        }
        sa_[t] = a; sb_[t] = b;
    }
    // pmm log-sum: sum_{k=1..m} 0.5*log((2k+1)/(2k))
    lg[t] = (t >= 1 && t <= m) ? 0.5 * log1p(0.5 / (double)t) : 0.0;
    __syncthreads();
    for (int s = 128; s > 0; s >>= 1) {
        if (t < s) lg[t] += lg[t + s];
        __syncthreads();
    }
    double sumlog = lg[0];

    // Tricomi initial guess (verified round 9: passes with 2 Newton sweeps)
    const double dn = 256.0;
    double theta = M_PI * (t + 0.75) / (dn + 0.5);
    double st = sin(theta);
    double x = (1.0 - (dn - 1.0) / (8.0 * dn * dn * dn)
                    - (39.0 - 28.0 / (st * st)) / (384.0 * dn * dn * dn * dn)) * cos(theta);
    double p1 = x, pd = 1.0;
    #pragma unroll 1
    for (int it = 0; it < 2; ++it) {
        double p0 = 1.0; p1 = x;
        #pragma unroll 4
        for (int k = 2; k <= 256; ++k) {
            double r = 1.0 / (double)k;           // independent of p-chain; pipelines
            double pk = ((2.0 - r) * x) * p1 - (1.0 - r) * p0;
            p0 = p1; p1 = pk;
        }
        pd = dn * (x * p1 - p0) / (x * x - 1.0);
        x -= p1 / pd;    // final iter: stale-pd weight err ~1e-6 rel (fp32-fine)
    }
    if (m == 0) w64[t] = 2.0 / ((1.0 - x * x) * pd * pd);

    // pmm = 1/sqrt(4pi) * (-1)^m * exp(sumlog) * sx^m  (7-step binary pow)
    double sx = sqrt(fmax(0.0, 1.0 - x * x));
    double prodm = exp(sumlog);
    if (m & 1) prodm = -prodm;
    double sxm = 1.0, bse = sx;
    int e = m;
    #pragma unroll
    for (int b7 = 0; b7 < 7; ++b7) { if (e & 1) sxm *= bse; bse *= bse; e >>= 1; }
    double pmm = 0.28209479177387814 * prodm * sxm;
    double pm1 = (m + 1 < 128) ? sqrt(2.0 * m + 3.0) * x * pmm : 0.0;

    // l-recurrence: direct LDS reads (round-8 form) + batched LmT float4 stores
    f16* Lm  = legh  + (size_t)m * 32768;
    f16* LmT = leghT + (size_t)m * 32768;
    double pprev = 0.0, pcur = 0.0;
    for (int g = 0; g < 16; ++g) {
        __align__(16) f16 tbuf[8];
        #pragma unroll
        for (int j = 0; j < 8; ++j) {
            int l = g * 8 + j;
            double v;
            if (l < m) v = 0.0;
            else if (l == m) v = pmm;
            else if (l == m + 1) v = pm1;
            else v = sa_[l] * (x * pcur - sb_[l] * pprev);
            if (l >= m) { pprev = pcur; pcur = v; }
            f16 h = (f16)v;
            Lm[l * 256 + t] = h;
            tbuf[j] = h;
        }
        *(float4*)(LmT + (size_t)t * 128 + g * 8) = *(float4*)tbuf;
    }
}

// ---------------- K_tables: CS[2][128][512] (cos*s | -sin*s), A5[512][512] --
// A5 columns k=510,511 are EXACTLY ZERO -> G pad rows need no zeroing.
__global__ void k_tables_h(f16* __restrict__ CS, f16* __restrict__ A5) {
    int tid = blockIdx.x * blockDim.x + threadIdx.x;
    const float w0 = (float)(2.0 * M_PI / 511.0);
    if (tid < 128 * 512) {
        int m = tid >> 9, p = tid & 511;
        float cv = 0.f, sv = 0.f;
        if (p < 511) {
            int r = (p * m) % 511;
            float ang = w0 * (float)r;
            cv = cosf(ang) * w0;
            sv = -sinf(ang) * w0;
        }
        CS[tid] = (f16)cv; CS[65536 + tid] = (f16)sv;
    }
    {
        int p = tid >> 9, k = tid & 511;
        float v = 0.f;
        if (p < 511 && k < 510) {
            int mp = k >> 1, mmv = mp - 127;
            int r = (p * mmv) % 511; if (r < 0) r += 511;
            float ang = w0 * (float)r;
            v = (k & 1) ? -sinf(ang) : cosf(ang);
        }
        A5[tid] = (f16)v;
    }
}

// ---------------- K_prep_R: phi(l) reduce + Rph[l][co][ci] = R*phi ----------
__global__ __launch_bounds__(256) void k_prep_R(const float* __restrict__ Rr, const float* __restrict__ Ri,
        const float* __restrict__ Ar, const float* __restrict__ Ai, const float* __restrict__ te,
        f16* __restrict__ Rphr, f16* __restrict__ Rphi) {
    __shared__ float srd[256], sid[256];
    int l = blockIdx.x, tid = threadIdx.x;
    float tv = te[tid];
    srd[tid] = Ar[l * 256 + tid] * tv;
    sid[tid] = Ai[l * 256 + tid] * tv;
    __syncthreads();
    for (int s = 128; s > 0; s >>= 1) {
        if (tid < s) { srd[tid] += srd[tid + s]; sid[tid] += sid[tid + s]; }
        __syncthreads();
    }
    float phr = srd[0], phii = sid[0];
    const float* rr = Rr + (size_t)l * 4096;
    const float* ri = Ri + (size_t)l * 4096;
    #pragma unroll
    for (int e = 0; e < 2; ++e) {
        int base = tid * 8 + e * 2048;
        float4 r0 = *(const float4*)(rr + base), r1 = *(const float4*)(rr + base + 4);
        float4 q0 = *(const float4*)(ri + base), q1 = *(const float4*)(ri + base + 4);
        __align__(16) f16 hr[8], hi[8];
        hr[0] = (f16)(r0.x * phr - q0.x * phii); hi[0] = (f16)(r0.x * phii + q0.x * phr);
        hr[1] = (f16)(r0.y * phr - q0.y * phii); hi[1] = (f16)(r0.y * phii + q0.y * phr);
        hr[2] = (f16)(r0.z * phr - q0.z * phii); hi[2] = (f16)(r0.z * phii + q0.z * phr);
        hr[3] = (f16)(r0.w * phr - q0.w * phii); hi[3] = (f16)(r0.w * phii + q0.w * phr);
        hr[4] = (f16)(r1.x * phr - q1.x * phii); hi[4] = (f16)(r1.x * phii + q1.x * phr);
        hr[5] = (f16)(r1.y * phr - q1.y * phii); hi[5] = (f16)(r1.y * phii + q1.y * phr);
        hr[6] = (f16)(r1.z * phr - q1.z * phii); hi[6] = (f16)(r1.z * phii + q1.z * phr);
        hr[7] = (f16)(r1.w * phr - q1.w * phii); hi[7] = (f16)(r1.w * phii + q1.w * phr);
        *(float4*)(Rphr + (size_t)l * 4096 + base) = *(float4*)hr;
        *(float4*)(Rphi + (size_t)l * 4096 + base) = *(float4*)hi;
    }
}

// ---------------- K_convert: x[t][p][c] f32 -> xh[t][c][p(512)] f16 ---------
__global__ __launch_bounds__(256) void k_convert(const float* __restrict__ x, f16* __restrict__ xh) {
    __shared__ float Ls[64][68];
    int t = blockIdx.x, pt = blockIdx.y, tid = threadIdx.x;
    int p0 = pt * 64;
    const float* xb = x + (size_t)t * (NPHI * 64);
    #pragma unroll
    for (int e = 0; e < 4; ++e) {
        int idx = tid + e * 256;
        int row = idx >> 4, c4 = (idx & 15) * 4;
        int p = p0 + row;
        float4 v = make_float4(0.f, 0.f, 0.f, 0.f);
        if (p < NPHI) v = *(const float4*)(xb + (size_t)p * 64 + c4);
        *(float4*)&Ls[row][c4] = v;
    }
    __syncthreads();
    #pragma unroll
    for (int e = 0; e < 2; ++e) {
        int idx = tid + e * 256;
        int c = idx >> 3, r8 = (idx & 7) * 8;
        __align__(16) f16 tmp[8];
        #pragma unroll
        for (int j = 0; j < 8; ++j) tmp[j] = (f16)Ls[r8 + j][c];
        *(float4*)(xh + (size_t)t * 32768 + (size_t)c * 512 + p0 + r8) = *(float4*)tmp;
    }
}

// ---------------- generic fp16 transpose tile body --------------------------
__device__ __forceinline__ void tr16_body(const f16* __restrict__ s, f16* __restrict__ d,
                                          int R, int C, int rt, int ct, int tid) {
    __shared__ f16 Ts[64][72];
    const f16* sp = s + (size_t)(rt * 64) * C + ct * 64;
    #pragma unroll
    for (int e = 0; e < 2; ++e) {
        int idx = tid + e * 256;
        int row = idx >> 3, c8 = (idx & 7) * 8;
        *(float4*)&Ts[row][c8] = *(const float4*)(sp + (size_t)row * C + c8);
    }
    __syncthreads();
    f16* dp = d + (size_t)(ct * 64) * R + rt * 64;
    #pragma unroll
    for (int e = 0; e < 2; ++e) {
        int idx = tid + e * 256;
        int c = idx >> 3, r8 = (idx & 7) * 8;
        __align__(16) f16 tmp[8];
        #pragma unroll
        for (int j = 0; j < 8; ++j) tmp[j] = Ts[r8 + j][c];
        *(float4*)(dp + (size_t)c * R + r8) = *(float4*)tmp;
    }
}

__global__ __launch_bounds__(256) void k_tr16(const f16* __restrict__ src, f16* __restrict__ dst,
                                              int R, int C) {
    int b = blockIdx.x, tile = blockIdx.y, tid = threadIdx.x;
    int ctiles = C >> 6;
    int rt = tile / ctiles, ct = tile - rt * ctiles;
    tr16_body(src + (size_t)b * R * C, dst + (size_t)b * R * C, R, C, rt, ct, tid);
}

__global__ __launch_bounds__(256) void k_trp(const f16* __restrict__ s0, f16* __restrict__ d0,
                                             const f16* __restrict__ s1, f16* __restrict__ d1,
                                             int R, int C, int sstr, int dstr) {
    int b = blockIdx.x, tile = blockIdx.y, tid = threadIdx.x;
    int ctiles = C >> 6;
    int rt = tile / ctiles, ct = tile - rt * ctiles;
    const f16* s = ((blockIdx.z == 0) ? s0 : s1) + (size_t)b * sstr;
    f16*       d = ((blockIdx.z == 0) ? d0 : d1) + (size_t)b * dstr;
    tr16_body(s, d, R, C, rt, ct, tid);
}

// ---------------- K_g1: stage 1 MFMA (64-tile, round-4 form) ----------------
__global__ __launch_bounds__(256) void k_g1(const f16* __restrict__ xh, const f16* __restrict__ cF,
        const f16* __restrict__ sF, const double* __restrict__ w64,
        f16* __restrict__ FwR, f16* __restrict__ FwI) {
    __shared__ f16 Ac[64][40], An[64][40], Bs[64][40];
    int t = blockIdx.x, mt = blockIdx.y, tid = threadIdx.x;
    const f16* A0 = cF + (size_t)(mt * 64) * 512;
    const f16* A1 = sF + (size_t)(mt * 64) * 512;
    const f16* B  = xh + (size_t)t * (64 * 512);
    f32x4 acc[2][2][2];  // [tab][mf][nf]
    #pragma unroll
    for (int a = 0; a < 2; ++a)
        #pragma unroll
        for (int b = 0; b < 2; ++b)
            #pragma unroll
            for (int c = 0; c < 2; ++c) acc[a][b][c] = (f32x4){0.f, 0.f, 0.f, 0.f};
    int lane = tid & 63, wid = tid >> 6;
    int wm = wid & 1, wn = wid >> 1;
    int fr = lane & 15, g8 = (lane >> 4) * 8;
    int row = tid >> 2, k8 = (tid & 3) * 8;
    for (int kt = 0; kt < 16; ++kt) {
        float4 va = *(const float4*)(A0 + (size_t)row * 512 + kt * 32 + k8);
        float4 vn = *(const float4*)(A1 + (size_t)row * 512 + kt * 32 + k8);
        float4 vb = *(const float4*)(B  + (size_t)row * 512 + kt * 32 + k8);
        __syncthreads();
        *(float4*)&Ac[row][k8] = va;
        *(float4*)&An[row][k8] = vn;
        *(float4*)&Bs[row][k8] = vb;
        __syncthreads();
        f16x8 b0 = *(f16x8*)&Bs[wn * 32 + fr][g8];
        f16x8 b1 = *(f16x8*)&Bs[wn * 32 + 16 + fr][g8];
        f16x8 a0 = *(f16x8*)&Ac[wm * 32 + fr][g8];
        f16x8 a1 = *(f16x8*)&Ac[wm * 32 + 16 + fr][g8];
        f16x8 s0 = *(f16x8*)&An[wm * 32 + fr][g8];
        f16x8 s1 = *(f16x8*)&An[wm * 32 + 16 + fr][g8];
        acc[0][0][0] = __builtin_amdgcn_mfma_f32_16x16x32_f16(a0, b0, acc[0][0][0], 0, 0, 0);
        acc[0][0][1] = __builtin_amdgcn_mfma_f32_16x16x32_f16(a0, b1, acc[0][0][1], 0, 0, 0);
        acc[0][1][0] = __builtin_amdgcn_mfma_f32_16x16x32_f16(a1, b0, acc[0][1][0], 0, 0, 0);
        acc[0][1][1] = __builtin_amdgcn_mfma_f32_16x16x32_f16(a1, b1, acc[0][1][1], 0, 0, 0);
        acc[1][0][0] = __builtin_amdgcn_mfma_f32_16x16x32_f16(s0, b0, acc[1][0][0], 0, 0, 0);
        acc[1][0][1] = __builtin_amdgcn_mfma_f32_16x16x32_f16(s0, b1, acc[1][0][1], 0, 0, 0);
        acc[1][1][0] = __builtin_amdgcn_mfma_f32_16x16x32_f16(s1, b0, acc[1][1][0], 0, 0, 0);
        acc[1][1][1] = __builtin_amdgcn_mfma_f32_16x16x32_f16(s1, b1, acc[1][1][1], 0, 0, 0);
    }
    float wf = (float)w64[t];
    int rg = (lane >> 4) * 4;
    #pragma unroll
    for (int mf = 0; mf < 2; ++mf)
        #pragma unroll
        for (int nf = 0; nf < 2; ++nf) {
            int c = wn * 32 + nf * 16 + fr;
            #pragma unroll
            for (int r = 0; r < 4; ++r) {
                int m = mt * 64 + wm * 32 + mf * 16 + rg + r;
                FwR[((size_t)m * 256 + t) * 64 + c] = (f16)(acc[0][mf][nf][r] * wf);
                FwI[((size_t)m * 256 + t) * 64 + c] = (f16)(acc[1][mf][nf][r] * wf);
            }
        }
}

// ---------------- K_g2: stage 2 MFMA (64-tile, round-4 form) ----------------
__global__ __launch_bounds__(256) void k_g2(const f16* __restrict__ legh, const f16* __restrict__ BTr,
        const f16* __restrict__ BTi, f16* __restrict__ Xhr, f16* __restrict__ Xhi) {
    __shared__ f16 As[64][40], Br[64][40], Bi[64][40];
    int m = blockIdx.x, lt = blockIdx.y, tid = threadIdx.x;
    const f16* A  = legh + (size_t)m * (128 * 256) + (size_t)(lt * 64) * 256;
    const f16* B0 = BTr + (size_t)m * (64 * 256);
    const f16* B1 = BTi + (size_t)m * (64 * 256);
    f32x4 acc[2][2][2];  // [bsel][mf][nf]
    #pragma unroll
    for (int a = 0; a < 2; ++a)
        #pragma unroll
        for (int b = 0; b < 2; ++b)
            #pragma unroll
            for (int c = 0; c < 2; ++c) acc[a][b][c] = (f32x4){0.f, 0.f, 0.f, 0.f};
    int lane = tid & 63, wid = tid >> 6;
    int wm = wid & 1, wn = wid >> 1;
    int fr = lane & 15, g8 = (lane >> 4) * 8;
    int row = tid >> 2, k8 = (tid & 3) * 8;
    for (int kt = 0; kt < 8; ++kt) {
        float4 va = *(const float4*)(A  + (size_t)row * 256 + kt * 32 + k8);
        float4 vr = *(const float4*)(B0 + (size_t)row * 256 + kt * 32 + k8);
        float4 vi = *(const float4*)(B1 + (size_t)row * 256 + kt * 32 + k8);
        __syncthreads();
        *(float4*)&As[row][k8] = va;
        *(float4*)&Br[row][k8] = vr;
        *(float4*)&Bi[row][k8] = vi;
        __syncthreads();
        f16x8 a0 = *(f16x8*)&As[wm * 32 + fr][g8];
        f16x8 a1 = *(f16x8*)&As[wm * 32 + 16 + fr][g8];
        f16x8 r0 = *(f16x8*)&Br[wn * 32 + fr][g8];
        f16x8 r1 = *(f16x8*)&Br[wn * 32 + 16 + fr][g8];
        f16x8 i0 = *(f16x8*)&Bi[wn * 32 + fr][g8];
        f16x8 i1 = *(f16x8*)&Bi[wn * 32 + 16 + fr][g8];
        acc[0][0][0] = __builtin_amdgcn_mfma_f32_16x16x32_f16(a0, r0, acc[0][0][0], 0, 0, 0);
        acc[0][0][1] = __builtin_amdgcn_mfma_f32_16x16x32_f16(a0, r1, acc[0][0][1], 0, 0, 0);
        acc[0][1][0] = __builtin_amdgcn_mfma_f32_16x16x32_f16(a1, r0, acc[0][1][0], 0, 0, 0);
        acc[0][1][1] = __builtin_amdgcn_mfma_f32_16x16x32_f16(a1, r1, acc[0][1][1], 0, 0, 0);
        acc[1][0][0] = __builtin_amdgcn_mfma_f32_16x16x32_f16(a0, i0, acc[1][0][0], 0, 0, 0);
        acc[1][0][1] = __builtin_amdgcn_mfma_f32_16x16x32_f16(a0, i1, acc[1][0][1], 0, 0, 0);
        acc[1][1][0] = __builtin_amdgcn_mfma_f32_16x16x32_f16(a1, i0, acc[1][1][0], 0, 0, 0);
        acc[1][1][1] = __builtin_amdgcn_mfma_f32_16x16x32_f16(a1, i1, acc[1][1][1], 0, 0, 0);
    }
    int rg = (lane >> 4) * 4;
    #pragma unroll
    for (int mf = 0; mf < 2; ++mf)
        #pragma unroll
        for (int nf = 0; nf < 2; ++nf) {
            int c = wn * 32 + nf * 16 + fr;
            #pragma unroll
            for (int r = 0; r < 4; ++r) {
                int l = lt * 64 + wm * 32 + mf * 16 + rg + r;
                Xhr[(size_t)m * 8192 + l * 64 + c] = (f16)acc[0][mf][nf][r];
                Xhi[(size_t)m * 8192 + l * 64 + c] = (f16)acc[1][mf][nf][r];
            }
        }
}

// ---------------- K_s3m: stage 3 MFMA (round-4 form) ------------------------
__global__ __launch_bounds__(256) void k_s3m(const f16* __restrict__ Xhr, const f16* __restrict__ Xhi,
        const f16* __restrict__ Rphr, const f16* __restrict__ Rphi,
        f16* __restrict__ Or, f16* __restrict__ Oi) {
    __shared__ f16 Ars[64][72], Ais[64][72], Ans[64][72];
    int l = blockIdx.x, mt = blockIdx.y, tid = threadIdx.x;
    {
        int arow = tid >> 2;
        int mp = mt * 64 + arow;
        int mmv = mp - 127, am = mmv < 0 ? -mmv : mmv;
        unsigned short cj = (mmv < 0) ? 0x8000 : 0;
        u16x8 cjv = {cj, cj, cj, cj, cj, cj, cj, cj};
        u16x8 ngv = {0x8000, 0x8000, 0x8000, 0x8000, 0x8000, 0x8000, 0x8000, 0x8000};
        #pragma unroll
        for (int e = 0; e < 2; ++e) {
            int ci8 = (tid & 3) * 8 + e * 32;
            u16x8 vr = {0, 0, 0, 0, 0, 0, 0, 0};
            u16x8 vi = {0, 0, 0, 0, 0, 0, 0, 0};
            if (mp < 255) {
                vr = *(const u16x8*)(Xhr + (size_t)am * 8192 + l * 64 + ci8);
                vi = *(const u16x8*)(Xhi + (size_t)am * 8192 + l * 64 + ci8);
            }
            u16x8 vic = vi ^ cjv;
            u16x8 vin = vic ^ ngv;
            *(u16x8*)&Ars[arow][ci8] = vr;
            *(u16x8*)&Ais[arow][ci8] = vic;
            *(u16x8*)&Ans[arow][ci8] = vin;
        }
    }
    __syncthreads();
    int lane = tid & 63, wid = tid >> 6;
    int wm = wid & 1, wn = wid >> 1;
    int fr = lane & 15, g8 = (lane >> 4) * 8;
    const f16* Bre = Rphr + (size_t)l * 4096;
    const f16* Bim = Rphi + (size_t)l * 4096;
    f32x4 accr[2][2], acci[2][2];
    #pragma unroll
    for (int a = 0; a < 2; ++a)
        #pragma unroll
        for (int b = 0; b < 2; ++b) { accr[a][b] = (f32x4){0.f,0.f,0.f,0.f}; acci[a][b] = (f32x4){0.f,0.f,0.f,0.f}; }
    #pragma unroll
    for (int ks = 0; ks < 2; ++ks) {
        int ko = ks * 32 + g8;
        f16x8 ar0 = *(f16x8*)&Ars[wm * 32 + fr][ko];
        f16x8 ar1 = *(f16x8*)&Ars[wm * 32 + 16 + fr][ko];
        f16x8 ai0 = *(f16x8*)&Ais[wm * 32 + fr][ko];
        f16x8 ai1 = *(f16x8*)&Ais[wm * 32 + 16 + fr][ko];
        f16x8 an0 = *(f16x8*)&Ans[wm * 32 + fr][ko];
        f16x8 an1 = *(f16x8*)&Ans[wm * 32 + 16 + fr][ko];
        #pragma unroll
        for (int nf = 0; nf < 2; ++nf) {
            int brow = wn * 32 + nf * 16 + fr;
            f16x8 br = *(const f16x8*)(Bre + (size_t)brow * 64 + ko);
            f16x8 bi = *(const f16x8*)(Bim + (size_t)brow * 64 + ko);
            accr[0][nf] = __builtin_amdgcn_mfma_f32_16x16x32_f16(ar0, br, accr[0][nf], 0, 0, 0);
            accr[0][nf] = __builtin_amdgcn_mfma_f32_16x16x32_f16(an0, bi, accr[0][nf], 0, 0, 0);
            acci[0][nf] = __builtin_amdgcn_mfma_f32_16x16x32_f16(ar0, bi, acci[0][nf], 0, 0, 0);
            acci[0][nf] = __builtin_amdgcn_mfma_f32_16x16x32_f16(ai0, br, acci[0][nf], 0, 0, 0);
            accr[1][nf] = __builtin_amdgcn_mfma_f32_16x16x32_f16(ar1, br, accr[1][nf], 0, 0, 0);
            accr[1][nf] = __builtin_amdgcn_mfma_f32_16x16x32_f16(an1, bi, accr[1][nf], 0, 0, 0);
            acci[1][nf] = __builtin_amdgcn_mfma_f32_16x16x32_f16(ar1, bi, acci[1][nf], 0, 0, 0);
            acci[1][nf] = __builtin_amdgcn_mfma_f32_16x16x32_f16(ai1, br, acci[1][nf], 0, 0, 0);
        }
    }
    int rg = (lane >> 4) * 4;
    #pragma unroll
    for (int mf = 0; mf < 2; ++mf)
        #pragma unroll
        for (int nf = 0; nf < 2; ++nf) {
            int co = wn * 32 + nf * 16 + fr;
            #pragma unroll
            for (int r = 0; r < 4; ++r) {
                int mp = mt * 64 + wm * 32 + mf * 16 + rg + r;
                if (mp < 255) {
                    Or[(size_t)mp * 8192 + l * 64 + co] = (f16)accr[mf][nf][r];
                    Oi[(size_t)mp * 8192 + l * 64 + co] = (f16)acci[mf][nf][r];
                }
            }
        }
}

// ---------------- K_g4: stage 4 MFMA (64-tile, round-4 form) ----------------
__global__ __launch_bounds__(256) void k_g4(const f16* __restrict__ legT, const f16* __restrict__ OTr,
        const f16* __restrict__ OTi, f16* __restrict__ G) {
    __shared__ f16 As[64][40], Br[64][40], Bi[64][40];
    int mp = blockIdx.x, tt = blockIdx.y, tid = threadIdx.x;
    int mmv = mp - 127, am = mmv < 0 ? -mmv : mmv;
    const f16* A  = legT + (size_t)am * (256 * 128) + (size_t)(tt * 64) * 128;
    const f16* B0 = OTr + (size_t)mp * (64 * 128);
    const f16* B1 = OTi + (size_t)mp * (64 * 128);
    f32x4 acc[2][2][2];
    #pragma unroll
    for (int a = 0; a < 2; ++a)
        #pragma unroll
        for (int b = 0; b < 2; ++b)
            #pragma unroll
            for (int c = 0; c < 2; ++c) acc[a][b][c] = (f32x4){0.f, 0.f, 0.f, 0.f};
    int lane = tid & 63, wid = tid >> 6;
    int wm = wid & 1, wn = wid >> 1;
    int fr = lane & 15, g8 = (lane >> 4) * 8;
    int row = tid >> 2, k8 = (tid & 3) * 8;
    for (int kt = am >> 5; kt < 4; ++kt) {
        float4 va = *(const float4*)(A  + (size_t)row * 128 + kt * 32 + k8);
        float4 vr = *(const float4*)(B0 + (size_t)row * 128 + kt * 32 + k8);
        float4 vi = *(const float4*)(B1 + (size_t)row * 128 + kt * 32 + k8);
        __syncthreads();
        *(float4*)&As[row][k8] = va;
        *(float4*)&Br[row][k8] = vr;
        *(float4*)&Bi[row][k8] = vi;
        __syncthreads();
        f16x8 a0 = *(f16x8*)&As[wm * 32 + fr][g8];
        f16x8 a1 = *(f16x8*)&As[wm * 32 + 16 + fr][g8];
        f16x8 r0 = *(f16x8*)&Br[wn * 32 + fr][g8];
        f16x8 r1 = *(f16x8*)&Br[wn * 32 + 16 + fr][g8];
        f16x8 i0 = *(f16x8*)&Bi[wn * 32 + fr][g8];
        f16x8 i1 = *(f16x8*)&Bi[wn * 32 + 16 + fr][g8];
        acc[0][0][0] = __builtin_amdgcn_mfma_f32_16x16x32_f16(a0, r0, acc[0][0][0], 0, 0, 0);
        acc[0][0][1] = __builtin_amdgcn_mfma_f32_16x16x32_f16(a0, r1, acc[0][0][1], 0, 0, 0);
        acc[0][1][0] = __builtin_amdgcn_mfma_f32_16x16x32_f16(a1, r0, acc[0][1][0], 0, 0, 0);
        acc[0][1][1] = __builtin_amdgcn_mfma_f32_16x16x32_f16(a1, r1, acc[0][1][1], 0, 0, 0);
        acc[1][0][0] = __builtin_amdgcn_mfma_f32_16x16x32_f16(a0, i0, acc[1][0][0], 0, 0, 0);
        acc[1][0][1] = __builtin_amdgcn_mfma_f32_16x16x32_f16(a0, i1, acc[1][0][1], 0, 0, 0);
        acc[1][1][0] = __builtin_amdgcn_mfma_f32_16x16x32_f16(a1, i0, acc[1][1][0], 0, 0, 0);
        acc[1][1][1] = __builtin_amdgcn_mfma_f32_16x16x32_f16(a1, i1, acc[1][1][1], 0, 0, 0);
    }
    int rg = (lane >> 4) * 4;
    f16* gr = G + (size_t)(2 * mp) * (256 * 64);
    f16* gi = G + (size_t)(2 * mp + 1) * (256 * 64);
    #pragma unroll
    for (int mf = 0; mf < 2; ++mf)
        #pragma unroll
        for (int nf = 0; nf < 2; ++nf) {
            int c = wn * 32 + nf * 16 + fr;
            #pragma unroll
            for (int r = 0; r < 4; ++r) {
                int tl = tt * 64 + wm * 32 + mf * 16 + rg + r;
                gr[(size_t)tl * 64 + c] = (f16)acc[0][mf][nf][r];
                gi[(size_t)tl * 64 + c] = (f16)acc[1][mf][nf][r];
            }
        }
}

// ---------------- K_g5: stage 5 MFMA (64-tile, round-4 form) ----------------
__global__ __launch_bounds__(256) void k_g5(const f16* __restrict__ A5, const f16* __restrict__ GT,
                                            float* __restrict__ out) {
    __shared__ f16 As[64][40], Bs[64][40];
    int t = blockIdx.x, pt = blockIdx.y, tid = threadIdx.x;
    const f16* A = A5 + (size_t)(pt * 64) * 512;
    const f16* B = GT + (size_t)t * (64 * 512);
    f32x4 acc[2][2];
    #pragma unroll
    for (int a = 0; a < 2; ++a)
        #pragma unroll
        for (int b = 0; b < 2; ++b) acc[a][b] = (f32x4){0.f, 0.f, 0.f, 0.f};
    int lane = tid & 63, wid = tid >> 6;
    int wm = wid & 1, wn = wid >> 1;
    int fr = lane & 15, g8 = (lane >> 4) * 8;
    int row = tid >> 2, k8 = (tid & 3) * 8;
    for (int kt = 0; kt < 16; ++kt) {
        float4 va = *(const float4*)(A + (size_t)row * 512 + kt * 32 + k8);
        float4 vb = *(const float4*)(B + (size_t)row * 512 + kt * 32 + k8);
        __syncthreads();
        *(float4*)&As[row][k8] = va;
        *(float4*)&Bs[row][k8] = vb;
        __syncthreads();
        f16x8 a0 = *(f16x8*)&As[wm * 32 + fr][g8];
        f16x8 a1 = *(f16x8*)&As[wm * 32 + 16 + fr][g8];
        f16x8 b0 = *(f16x8*)&Bs[wn * 32 + fr][g8];
        f16x8 b1 = *(f16x8*)&Bs[wn * 32 + 16 + fr][g8];
        acc[0][0] = __builtin_amdgcn_mfma_f32_16x16x32_f16(a0, b0, acc[0][0], 0, 0, 0);
        acc[0][1] = __builtin_amdgcn_mfma_f32_16x16x32_f16(a0, b1, acc[0][1], 0, 0, 0);
        acc[1][0] = __builtin_amdgcn_mfma_f32_16x16x32_f16(a1, b0, acc[1][0], 0, 0, 0);
        acc[1][1] = __builtin_amdgcn_mfma_f32_16x16x32_f16(a1, b1, acc[1][1], 0, 0, 0);
    }
    int rg = (lane >> 4) * 4;
    #pragma unroll
    for (int mf = 0; mf < 2; ++mf)
        #pragma unroll
        for (int nf = 0; nf < 2; ++nf) {
            int c = wn * 32 + nf * 16 + fr;
            #pragma unroll
            for (int r = 0; r < 4; ++r) {
                int p = pt * 64 + wm * 32 + mf * 16 + rg + r;
                if (p < NPHI) out[((size_t)t * NPHI + p) * 64 + c] = acc[mf][nf][r];
            }
        }
}

extern "C" void kernel_launch(void* const* d_in, const int* in_sizes, int n_in,
                              void* d_out, int out_size, void* d_ws, size_t ws_size,
                              hipStream_t stream) {
    const float* x    = (const float*)d_in[0];
    const float* temb = (const float*)d_in[1];
    const float* Ar   = (const float*)d_in[2];
    const float* Ai   = (const float*)d_in[3];
    const float* Rr   = (const float*)d_in[4];
    const float* Ri   = (const float*)d_in[5];
    float* out = (float*)d_out;

    char* ws = (char*)d_ws;
    size_t off = 0;
    auto alloc = [&](size_t bytes) -> void* {
        void* p = ws + off;
        off = (off + bytes + 255) & ~(size_t)255;
        return p;
    };
    double* w64  = (double*)alloc(256 * 8);
    f16* legh   = (f16*)alloc((size_t)128 * 128 * 256 * 2);   // 8.39 MB
    f16* leghT  = (f16*)alloc((size_t)128 * 256 * 128 * 2);   // 8.39 MB
    f16* CS     = (f16*)alloc((size_t)2 * 128 * 512 * 2);     // 256 KB (cF | sF)
    f16* A5     = (f16*)alloc((size_t)512 * 512 * 2);         // 512 KB
    f16* Rphr   = (f16*)alloc((size_t)128 * 64 * 64 * 2);     // 1.05 MB
    f16* Rphi   = (f16*)alloc((size_t)128 * 64 * 64 * 2);
    f16* R1     = (f16*)alloc((size_t)256 * 64 * 512 * 2);    // 16.78 MB: xh -> GT
    f16* R2     = (f16*)alloc((size_t)512 * 256 * 64 * 2);    // 16.78 MB: Fw{R,I,RT,IT} -> Gk
    f16* Xhr    = (f16*)alloc((size_t)128 * 128 * 64 * 2);    // 2.1 MB
    f16* Xhi    = (f16*)alloc((size_t)128 * 128 * 64 * 2);
    f16* Or     = (f16*)alloc((size_t)255 * 128 * 64 * 2);    // 4.18 MB
    f16* Oi     = (f16*)alloc((size_t)255 * 128 * 64 * 2);
    f16* OrT    = (f16*)alloc((size_t)255 * 64 * 128 * 2);
    f16* OiT    = (f16*)alloc((size_t)255 * 64 * 128 * 2);
    if (off > ws_size) return;

    f16* xh   = R1;
    f16* GT   = R1;
    f16* FwR  = R2;
    f16* FwI  = R2 + (size_t)2097152;
    f16* FwRT = R2 + (size_t)4194304;
    f16* FwIT = R2 + (size_t)6291456;
    f16* Gk   = R2;   // rows 510,511 stale-but-finite; A5 cols 510,511 == 0
    f16* cF   = CS;
    f16* sF   = CS + (size_t)65536;

    hipLaunchKernelGGL(k_leg,      dim3(128),        dim3(256), 0, stream, legh, leghT, w64);
    hipLaunchKernelGGL(k_tables_h, dim3(1024),       dim3(256), 0, stream, CS, A5);
    hipLaunchKernelGGL(k_prep_R,   dim3(128),        dim3(256), 0, stream, Rr, Ri, Ar, Ai, temb, Rphr, Rphi);
    hipLaunchKernelGGL(k_convert,  dim3(256, 8),     dim3(256), 0, stream, x, xh);
    hipLaunchKernelGGL(k_g1,       dim3(256, 2),     dim3(256), 0, stream, xh, cF, sF, w64, FwR, FwI);
    hipLaunchKernelGGL(k_trp,      dim3(128, 4, 2),  dim3(256), 0, stream, FwR, FwRT, FwI, FwIT, 256, 64, 16384, 16384);
    hipLaunchKernelGGL(k_g2,       dim3(128, 2),     dim3(256), 0, stream, legh, FwRT, FwIT, Xhr, Xhi);
    hipLaunchKernelGGL(k_s3m,      dim3(128, 4),     dim3(256), 0, stream, Xhr, Xhi, Rphr, Rphi, Or, Oi);
    hipLaunchKernelGGL(k_trp,      dim3(255, 2, 2),  dim3(256), 0, stream, Or, OrT, Oi, OiT, 128, 64, 8192, 8192);
    hipLaunchKernelGGL(k_g4,       dim3(255, 4),     dim3(256), 0, stream, leghT, OrT, OiT, Gk);
    hipLaunchKernelGGL(k_tr16,     dim3(1, 2048),    dim3(256), 0, stream, Gk, GT, 512, 16384);
    hipLaunchKernelGGL(k_g5,       dim3(256, 8),     dim3(256), 0, stream, A5, GT, out);
}

// Round 11
// 124.779 us; speedup vs baseline: 2.3145x; 1.1735x over previous
//
#include <hip/hip_runtime.h>
#include <math.h>

#ifndef M_PI
#define M_PI 3.14159265358979323846
#endif

typedef _Float16 f16;
typedef _Float16 f16x8 __attribute__((ext_vector_type(8)));
typedef unsigned short u16x8 __attribute__((ext_vector_type(8)));
typedef float f32x4 __attribute__((ext_vector_type(4)));

#define NPHI 511
#define NM   255

// ---------------- K_leg: GL nodes + legh + leghT + w64 ----------------------
// Tricomi init + 2 Newton sweeps. Recurrence coefficients packed as fp32
// float4 pairs in LDS: 4 independent ds_read_b128 per 8 chain steps (batched,
// latency-amortized) + fp64 chain. Round-9 (reg arrays) spilled; round-10
// (in-loop fp64 div) was issue-bound at 53us. fp32 coeffs: node err ~1e-9.
__global__ __launch_bounds__(256) void k_leg(f16* __restrict__ legh, f16* __restrict__ leghT,
                                             double* __restrict__ w64) {
    __shared__ float4 ct4[128];    // (c1,c2) for k=2+2i, 3+2i
    __shared__ float4 sab4[64];    // (sa,sb) for l=2i, 2i+1
    __shared__ double lg[256];
    int m = blockIdx.x, t = threadIdx.x;
    if (t < 128) {
        int k0 = 2 + 2 * t, k1 = 3 + 2 * t;
        ct4[t] = make_float4((float)((2.0 * k0 - 1.0) / k0), (float)((k0 - 1.0) / (double)k0),
                             (float)((2.0 * k1 - 1.0) / k1), (float)((k1 - 1.0) / (double)k1));
    } else {
        int i = t - 128;           // 0..127 -> l pairs
        if (i < 64) {
            int l0 = 2 * i, l1 = 2 * i + 1;
            float a0 = 1.f, b0 = 0.f, a1 = 1.f, b1 = 0.f;
            double dm = m;
            if (l0 >= 2) {
                double dl = l0;
                a0 = (float)sqrt((4.0 * dl * dl - 1.0) / (dl * dl - dm * dm));
                b0 = (float)sqrt(((dl - 1.0) * (dl - 1.0) - dm * dm) / (4.0 * (dl - 1.0) * (dl - 1.0) - 1.0));
            }
            if (l1 >= 2) {
                double dl = l1;
                a1 = (float)sqrt((4.0 * dl * dl - 1.0) / (dl * dl - dm * dm));
                b1 = (float)sqrt(((dl - 1.0) * (dl - 1.0) - dm * dm) / (4.0 * (dl - 1.0) * (dl - 1.0) - 1.0));
            }
            sab4[i] = make_float4(a0, b0, a1, b1);
        }
    }
    // pmm log-sum: sum_{k=1..m} 0.5*log((2k+1)/(2k))
    lg[t] = (t >= 1 && t <= m) ? 0.5 * log1p(0.5 / (double)t) : 0.0;
    __syncthreads();
    for (int s = 128; s > 0; s >>= 1) {
        if (t < s) lg[t] += lg[t + s];
        __syncthreads();
    }
    double sumlog = lg[0];

    // Tricomi initial guess (verified rounds 9-10: passes with 2 Newton sweeps)
    const double dn = 256.0;
    double theta = M_PI * (t + 0.75) / (dn + 0.5);
    double st = sin(theta);
    double x = (1.0 - (dn - 1.0) / (8.0 * dn * dn * dn)
                    - (39.0 - 28.0 / (st * st)) / (384.0 * dn * dn * dn * dn)) * cos(theta);

#define NSTEP(C1, C2) { double pk = (double)(C1) * x * p1 - (double)(C2) * p0; p0 = p1; p1 = pk; }
    double p1 = x, pd = 1.0;
    #pragma unroll 1
    for (int it = 0; it < 2; ++it) {
        double p0 = 1.0; p1 = x;
        #pragma unroll 1
        for (int g = 0; g < 31; ++g) {    // k = 2+8g .. 9+8g  (248 steps)
            float4 q0 = ct4[4 * g + 0], q1 = ct4[4 * g + 1];
            float4 q2 = ct4[4 * g + 2], q3 = ct4[4 * g + 3];
            NSTEP(q0.x, q0.y) NSTEP(q0.z, q0.w) NSTEP(q1.x, q1.y) NSTEP(q1.z, q1.w)
            NSTEP(q2.x, q2.y) NSTEP(q2.z, q2.w) NSTEP(q3.x, q3.y) NSTEP(q3.z, q3.w)
        }
        {   // tail k=250..256 (7 steps)
            float4 q0 = ct4[124], q1 = ct4[125], q2 = ct4[126], q3 = ct4[127];
            NSTEP(q0.x, q0.y) NSTEP(q0.z, q0.w) NSTEP(q1.x, q1.y) NSTEP(q1.z, q1.w)
            NSTEP(q2.x, q2.y) NSTEP(q2.z, q2.w) NSTEP(q3.x, q3.y)
        }
        pd = dn * (x * p1 - p0) / (x * x - 1.0);
        x -= p1 / pd;    // final iter: stale-pd weight err negligible (verified)
    }
#undef NSTEP
    if (m == 0) w64[t] = 2.0 / ((1.0 - x * x) * pd * pd);

    // pmm = 1/sqrt(4pi) * (-1)^m * exp(sumlog) * sx^m  (7-step binary pow)
    double sx = sqrt(fmax(0.0, 1.0 - x * x));
    double prodm = exp(sumlog);
    if (m & 1) prodm = -prodm;
    double sxm = 1.0, bse = sx;
    int e = m;
    #pragma unroll
    for (int b7 = 0; b7 < 7; ++b7) { if (e & 1) sxm *= bse; bse *= bse; e >>= 1; }
    double pmm = 0.28209479177387814 * prodm * sxm;
    double pm1 = (m + 1 < 128) ? sqrt(2.0 * m + 3.0) * x * pmm : 0.0;

    // l-recurrence: 8 l's per group, 4 batched float4 coefficient reads
    f16* Lm  = legh  + (size_t)m * 32768;
    f16* LmT = leghT + (size_t)m * 32768;
    double pprev = 0.0, pcur = 0.0;
#define LSTEP(J, SA, SB) { int l = h * 8 + (J); double v; \
        if (l < m) v = 0.0; \
        else if (l == m) v = pmm; \
        else if (l == m + 1) v = pm1; \
        else v = (double)(SA) * (x * pcur - (double)(SB) * pprev); \
        if (l >= m) { pprev = pcur; pcur = v; } \
        f16 hh = (f16)v; Lm[l * 256 + t] = hh; tbuf[J] = hh; }
    #pragma unroll 1
    for (int h = 0; h < 16; ++h) {
        float4 s0 = sab4[4 * h + 0], s1 = sab4[4 * h + 1];
        float4 s2 = sab4[4 * h + 2], s3 = sab4[4 * h + 3];
        __align__(16) f16 tbuf[8];
        LSTEP(0, s0.x, s0.y) LSTEP(1, s0.z, s0.w) LSTEP(2, s1.x, s1.y) LSTEP(3, s1.z, s1.w)
        LSTEP(4, s2.x, s2.y) LSTEP(5, s2.z, s2.w) LSTEP(6, s3.x, s3.y) LSTEP(7, s3.z, s3.w)
        *(float4*)(LmT + (size_t)t * 128 + h * 8) = *(float4*)tbuf;
    }
#undef LSTEP
}

// ---------------- K_tables: CS[2][128][512] (cos*s | -sin*s), A5[512][512] --
// A5 columns k=510,511 are EXACTLY ZERO -> G pad rows need no zeroing.
__global__ void k_tables_h(f16* __restrict__ CS, f16* __restrict__ A5) {
    int tid = blockIdx.x * blockDim.x + threadIdx.x;
    const float w0 = (float)(2.0 * M_PI / 511.0);
    if (tid < 128 * 512) {
        int m = tid >> 9, p = tid & 511;
        float cv = 0.f, sv = 0.f;
        if (p < 511) {
            int r = (p * m) % 511;
            float ang = w0 * (float)r;
            cv = cosf(ang) * w0;
            sv = -sinf(ang) * w0;
        }
        CS[tid] = (f16)cv; CS[65536 + tid] = (f16)sv;
    }
    {
        int p = tid >> 9, k = tid & 511;
        float v = 0.f;
        if (p < 511 && k < 510) {
            int mp = k >> 1, mmv = mp - 127;
            int r = (p * mmv) % 511; if (r < 0) r += 511;
            float ang = w0 * (float)r;
            v = (k & 1) ? -sinf(ang) : cosf(ang);
        }
        A5[tid] = (f16)v;
    }
}

// ---------------- K_prep_R: phi(l) reduce + Rph[l][co][ci] = R*phi ----------
__global__ __launch_bounds__(256) void k_prep_R(const float* __restrict__ Rr, const float* __restrict__ Ri,
        const float* __restrict__ Ar, const float* __restrict__ Ai, const float* __restrict__ te,
        f16* __restrict__ Rphr, f16* __restrict__ Rphi) {
    __shared__ float srd[256], sid[256];
    int l = blockIdx.x, tid = threadIdx.x;
    float tv = te[tid];
    srd[tid] = Ar[l * 256 + tid] * tv;
    sid[tid] = Ai[l * 256 + tid] * tv;
    __syncthreads();
    for (int s = 128; s > 0; s >>= 1) {
        if (tid < s) { srd[tid] += srd[tid + s]; sid[tid] += sid[tid + s]; }
        __syncthreads();
    }
    float phr = srd[0], phii = sid[0];
    const float* rr = Rr + (size_t)l * 4096;
    const float* ri = Ri + (size_t)l * 4096;
    #pragma unroll
    for (int e = 0; e < 2; ++e) {
        int base = tid * 8 + e * 2048;
        float4 r0 = *(const float4*)(rr + base), r1 = *(const float4*)(rr + base + 4);
        float4 q0 = *(const float4*)(ri + base), q1 = *(const float4*)(ri + base + 4);
        __align__(16) f16 hr[8], hi[8];
        hr[0] = (f16)(r0.x * phr - q0.x * phii); hi[0] = (f16)(r0.x * phii + q0.x * phr);
        hr[1] = (f16)(r0.y * phr - q0.y * phii); hi[1] = (f16)(r0.y * phii + q0.y * phr);
        hr[2] = (f16)(r0.z * phr - q0.z * phii); hi[2] = (f16)(r0.z * phii + q0.z * phr);
        hr[3] = (f16)(r0.w * phr - q0.w * phii); hi[3] = (f16)(r0.w * phii + q0.w * phr);
        hr[4] = (f16)(r1.x * phr - q1.x * phii); hi[4] = (f16)(r1.x * phii + q1.x * phr);
        hr[5] = (f16)(r1.y * phr - q1.y * phii); hi[5] = (f16)(r1.y * phii + q1.y * phr);
        hr[6] = (f16)(r1.z * phr - q1.z * phii); hi[6] = (f16)(r1.z * phii + q1.z * phr);
        hr[7] = (f16)(r1.w * phr - q1.w * phii); hi[7] = (f16)(r1.w * phii + q1.w * phr);
        *(float4*)(Rphr + (size_t)l * 4096 + base) = *(float4*)hr;
        *(float4*)(Rphi + (size_t)l * 4096 + base) = *(float4*)hi;
    }
}

// ---------------- K_convert: x[t][p][c] f32 -> xh[t][c][p(512)] f16 ---------
__global__ __launch_bounds__(256) void k_convert(const float* __restrict__ x, f16* __restrict__ xh) {
    __shared__ float Ls[64][68];
    int t = blockIdx.x, pt = blockIdx.y, tid = threadIdx.x;
    int p0 = pt * 64;
    const float* xb = x + (size_t)t * (NPHI * 64);
    #pragma unroll
    for (int e = 0; e < 4; ++e) {
        int idx = tid + e * 256;
        int row = idx >> 4, c4 = (idx & 15) * 4;
        int p = p0 + row;
        float4 v = make_float4(0.f, 0.f, 0.f, 0.f);
        if (p < NPHI) v = *(const float4*)(xb + (size_t)p * 64 + c4);
        *(float4*)&Ls[row][c4] = v;
    }
    __syncthreads();
    #pragma unroll
    for (int e = 0; e < 2; ++e) {
        int idx = tid + e * 256;
        int c = idx >> 3, r8 = (idx & 7) * 8;
        __align__(16) f16 tmp[8];
        #pragma unroll
        for (int j = 0; j < 8; ++j) tmp[j] = (f16)Ls[r8 + j][c];
        *(float4*)(xh + (size_t)t * 32768 + (size_t)c * 512 + p0 + r8) = *(float4*)tmp;
    }
}

// ---------------- generic fp16 transpose tile body --------------------------
__device__ __forceinline__ void tr16_body(const f16* __restrict__ s, f16* __restrict__ d,
                                          int R, int C, int rt, int ct, int tid) {
    __shared__ f16 Ts[64][72];
    const f16* sp = s + (size_t)(rt * 64) * C + ct * 64;
    #pragma unroll
    for (int e = 0; e < 2; ++e) {
        int idx = tid + e * 256;
        int row = idx >> 3, c8 = (idx & 7) * 8;
        *(float4*)&Ts[row][c8] = *(const float4*)(sp + (size_t)row * C + c8);
    }
    __syncthreads();
    f16* dp = d + (size_t)(ct * 64) * R + rt * 64;
    #pragma unroll
    for (int e = 0; e < 2; ++e) {
        int idx = tid + e * 256;
        int c = idx >> 3, r8 = (idx & 7) * 8;
        __align__(16) f16 tmp[8];
        #pragma unroll
        for (int j = 0; j < 8; ++j) tmp[j] = Ts[r8 + j][c];
        *(float4*)(dp + (size_t)c * R + r8) = *(float4*)tmp;
    }
}

__global__ __launch_bounds__(256) void k_tr16(const f16* __restrict__ src, f16* __restrict__ dst,
                                              int R, int C) {
    int b = blockIdx.x, tile = blockIdx.y, tid = threadIdx.x;
    int ctiles = C >> 6;
    int rt = tile / ctiles, ct = tile - rt * ctiles;
    tr16_body(src + (size_t)b * R * C, dst + (size_t)b * R * C, R, C, rt, ct, tid);
}

__global__ __launch_bounds__(256) void k_trp(const f16* __restrict__ s0, f16* __restrict__ d0,
                                             const f16* __restrict__ s1, f16* __restrict__ d1,
                                             int R, int C, int sstr, int dstr) {
    int b = blockIdx.x, tile = blockIdx.y, tid = threadIdx.x;
    int ctiles = C >> 6;
    int rt = tile / ctiles, ct = tile - rt * ctiles;
    const f16* s = ((blockIdx.z == 0) ? s0 : s1) + (size_t)b * sstr;
    f16*       d = ((blockIdx.z == 0) ? d0 : d1) + (size_t)b * dstr;
    tr16_body(s, d, R, C, rt, ct, tid);
}

// ---------------- K_g1: stage 1 MFMA (64-tile, round-4 form) ----------------
__global__ __launch_bounds__(256) void k_g1(const f16* __restrict__ xh, const f16* __restrict__ cF,
        const f16* __restrict__ sF, const double* __restrict__ w64,
        f16* __restrict__ FwR, f16* __restrict__ FwI) {
    __shared__ f16 Ac[64][40], An[64][40], Bs[64][40];
    int t = blockIdx.x, mt = blockIdx.y, tid = threadIdx.x;
    const f16* A0 = cF + (size_t)(mt * 64) * 512;
    const f16* A1 = sF + (size_t)(mt * 64) * 512;
    const f16* B  = xh + (size_t)t * (64 * 512);
    f32x4 acc[2][2][2];  // [tab][mf][nf]
    #pragma unroll
    for (int a = 0; a < 2; ++a)
        #pragma unroll
        for (int b = 0; b < 2; ++b)
            #pragma unroll
            for (int c = 0; c < 2; ++c) acc[a][b][c] = (f32x4){0.f, 0.f, 0.f, 0.f};
    int lane = tid & 63, wid = tid >> 6;
    int wm = wid & 1, wn = wid >> 1;
    int fr = lane & 15, g8 = (lane >> 4) * 8;
    int row = tid >> 2, k8 = (tid & 3) * 8;
    for (int kt = 0; kt < 16; ++kt) {
        float4 va = *(const float4*)(A0 + (size_t)row * 512 + kt * 32 + k8);
        float4 vn = *(const float4*)(A1 + (size_t)row * 512 + kt * 32 + k8);
        float4 vb = *(const float4*)(B  + (size_t)row * 512 + kt * 32 + k8);
        __syncthreads();
        *(float4*)&Ac[row][k8] = va;
        *(float4*)&An[row][k8] = vn;
        *(float4*)&Bs[row][k8] = vb;
        __syncthreads();
        f16x8 b0 = *(f16x8*)&Bs[wn * 32 + fr][g8];
        f16x8 b1 = *(f16x8*)&Bs[wn * 32 + 16 + fr][g8];
        f16x8 a0 = *(f16x8*)&Ac[wm * 32 + fr][g8];
        f16x8 a1 = *(f16x8*)&Ac[wm * 32 + 16 + fr][g8];
        f16x8 s0 = *(f16x8*)&An[wm * 32 + fr][g8];
        f16x8 s1 = *(f16x8*)&An[wm * 32 + 16 + fr][g8];
        acc[0][0][0] = __builtin_amdgcn_mfma_f32_16x16x32_f16(a0, b0, acc[0][0][0], 0, 0, 0);
        acc[0][0][1] = __builtin_amdgcn_mfma_f32_16x16x32_f16(a0, b1, acc[0][0][1], 0, 0, 0);
        acc[0][1][0] = __builtin_amdgcn_mfma_f32_16x16x32_f16(a1, b0, acc[0][1][0], 0, 0, 0);
        acc[0][1][1] = __builtin_amdgcn_mfma_f32_16x16x32_f16(a1, b1, acc[0][1][1], 0, 0, 0);
        acc[1][0][0] = __builtin_amdgcn_mfma_f32_16x16x32_f16(s0, b0, acc[1][0][0], 0, 0, 0);
        acc[1][0][1] = __builtin_amdgcn_mfma_f32_16x16x32_f16(s0, b1, acc[1][0][1], 0, 0, 0);
        acc[1][1][0] = __builtin_amdgcn_mfma_f32_16x16x32_f16(s1, b0, acc[1][1][0], 0, 0, 0);
        acc[1][1][1] = __builtin_amdgcn_mfma_f32_16x16x32_f16(s1, b1, acc[1][1][1], 0, 0, 0);
    }
    float wf = (float)w64[t];
    int rg = (lane >> 4) * 4;
    #pragma unroll
    for (int mf = 0; mf < 2; ++mf)
        #pragma unroll
        for (int nf = 0; nf < 2; ++nf) {
            int c = wn * 32 + nf * 16 + fr;
            #pragma unroll
            for (int r = 0; r < 4; ++r) {
                int m = mt * 64 + wm * 32 + mf * 16 + rg + r;
                FwR[((size_t)m * 256 + t) * 64 + c] = (f16)(acc[0][mf][nf][r] * wf);
                FwI[((size_t)m * 256 + t) * 64 + c] = (f16)(acc[1][mf][nf][r] * wf);
            }
        }
}

// ---------------- K_g2: stage 2 MFMA (64-tile, round-4 form) ----------------
__global__ __launch_bounds__(256) void k_g2(const f16* __restrict__ legh, const f16* __restrict__ BTr,
        const f16* __restrict__ BTi, f16* __restrict__ Xhr, f16* __restrict__ Xhi) {
    __shared__ f16 As[64][40], Br[64][40], Bi[64][40];
    int m = blockIdx.x, lt = blockIdx.y, tid = threadIdx.x;
    const f16* A  = legh + (size_t)m * (128 * 256) + (size_t)(lt * 64) * 256;
    const f16* B0 = BTr + (size_t)m * (64 * 256);
    const f16* B1 = BTi + (size_t)m * (64 * 256);
    f32x4 acc[2][2][2];  // [bsel][mf][nf]
    #pragma unroll
    for (int a = 0; a < 2; ++a)
        #pragma unroll
        for (int b = 0; b < 2; ++b)
            #pragma unroll
            for (int c = 0; c < 2; ++c) acc[a][b][c] = (f32x4){0.f, 0.f, 0.f, 0.f};
    int lane = tid & 63, wid = tid >> 6;
    int wm = wid & 1, wn = wid >> 1;
    int fr = lane & 15, g8 = (lane >> 4) * 8;
    int row = tid >> 2, k8 = (tid & 3) * 8;
    for (int kt = 0; kt < 8; ++kt) {
        float4 va = *(const float4*)(A  + (size_t)row * 256 + kt * 32 + k8);
        float4 vr = *(const float4*)(B0 + (size_t)row * 256 + kt * 32 + k8);
        float4 vi = *(const float4*)(B1 + (size_t)row * 256 + kt * 32 + k8);
        __syncthreads();
        *(float4*)&As[row][k8] = va;
        *(float4*)&Br[row][k8] = vr;
        *(float4*)&Bi[row][k8] = vi;
        __syncthreads();
        f16x8 a0 = *(f16x8*)&As[wm * 32 + fr][g8];
        f16x8 a1 = *(f16x8*)&As[wm * 32 + 16 + fr][g8];
        f16x8 r0 = *(f16x8*)&Br[wn * 32 + fr][g8];
        f16x8 r1 = *(f16x8*)&Br[wn * 32 + 16 + fr][g8];
        f16x8 i0 = *(f16x8*)&Bi[wn * 32 + fr][g8];
        f16x8 i1 = *(f16x8*)&Bi[wn * 32 + 16 + fr][g8];
        acc[0][0][0] = __builtin_amdgcn_mfma_f32_16x16x32_f16(a0, r0, acc[0][0][0], 0, 0, 0);
        acc[0][0][1] = __builtin_amdgcn_mfma_f32_16x16x32_f16(a0, r1, acc[0][0][1], 0, 0, 0);
        acc[0][1][0] = __builtin_amdgcn_mfma_f32_16x16x32_f16(a1, r0, acc[0][1][0], 0, 0, 0);
        acc[0][1][1] = __builtin_amdgcn_mfma_f32_16x16x32_f16(a1, r1, acc[0][1][1], 0, 0, 0);
        acc[1][0][0] = __builtin_amdgcn_mfma_f32_16x16x32_f16(a0, i0, acc[1][0][0], 0, 0, 0);
        acc[1][0][1] = __builtin_amdgcn_mfma_f32_16x16x32_f16(a0, i1, acc[1][0][1], 0, 0, 0);
        acc[1][1][0] = __builtin_amdgcn_mfma_f32_16x16x32_f16(a1, i0, acc[1][1][0], 0, 0, 0);
        acc[1][1][1] = __builtin_amdgcn_mfma_f32_16x16x32_f16(a1, i1, acc[1][1][1], 0, 0, 0);
    }
    int rg = (lane >> 4) * 4;
    #pragma unroll
    for (int mf = 0; mf < 2; ++mf)
        #pragma unroll
        for (int nf = 0; nf < 2; ++nf) {
            int c = wn * 32 + nf * 16 + fr;
            #pragma unroll
            for (int r = 0; r < 4; ++r) {
                int l = lt * 64 + wm * 32 + mf * 16 + rg + r;
                Xhr[(size_t)m * 8192 + l * 64 + c] = (f16)acc[0][mf][nf][r];
                Xhi[(size_t)m * 8192 + l * 64 + c] = (f16)acc[1][mf][nf][r];
            }
        }
}

// ---------------- K_s3m: stage 3 MFMA (round-4 form) ------------------------
__global__ __launch_bounds__(256) void k_s3m(const f16* __restrict__ Xhr, const f16* __restrict__ Xhi,
        const f16* __restrict__ Rphr, const f16* __restrict__ Rphi,
        f16* __restrict__ Or, f16* __restrict__ Oi) {
    __shared__ f16 Ars[64][72], Ais[64][72], Ans[64][72];
    int l = blockIdx.x, mt = blockIdx.y, tid = threadIdx.x;
    {
        int arow = tid >> 2;
        int mp = mt * 64 + arow;
        int mmv = mp - 127, am = mmv < 0 ? -mmv : mmv;
        unsigned short cj = (mmv < 0) ? 0x8000 : 0;
        u16x8 cjv = {cj, cj, cj, cj, cj, cj, cj, cj};
        u16x8 ngv = {0x8000, 0x8000, 0x8000, 0x8000, 0x8000, 0x8000, 0x8000, 0x8000};
        #pragma unroll
        for (int e = 0; e < 2; ++e) {
            int ci8 = (tid & 3) * 8 + e * 32;
            u16x8 vr = {0, 0, 0, 0, 0, 0, 0, 0};
            u16x8 vi = {0, 0, 0, 0, 0, 0, 0, 0};
            if (mp < 255) {
                vr = *(const u16x8*)(Xhr + (size_t)am * 8192 + l * 64 + ci8);
                vi = *(const u16x8*)(Xhi + (size_t)am * 8192 + l * 64 + ci8);
            }
            u16x8 vic = vi ^ cjv;
            u16x8 vin = vic ^ ngv;
            *(u16x8*)&Ars[arow][ci8] = vr;
            *(u16x8*)&Ais[arow][ci8] = vic;
            *(u16x8*)&Ans[arow][ci8] = vin;
        }
    }
    __syncthreads();
    int lane = tid & 63, wid = tid >> 6;
    int wm = wid & 1, wn = wid >> 1;
    int fr = lane & 15, g8 = (lane >> 4) * 8;
    const f16* Bre = Rphr + (size_t)l * 4096;
    const f16* Bim = Rphi + (size_t)l * 4096;
    f32x4 accr[2][2], acci[2][2];
    #pragma unroll
    for (int a = 0; a < 2; ++a)
        #pragma unroll
        for (int b = 0; b < 2; ++b) { accr[a][b] = (f32x4){0.f,0.f,0.f,0.f}; acci[a][b] = (f32x4){0.f,0.f,0.f,0.f}; }
    #pragma unroll
    for (int ks = 0; ks < 2; ++ks) {
        int ko = ks * 32 + g8;
        f16x8 ar0 = *(f16x8*)&Ars[wm * 32 + fr][ko];
        f16x8 ar1 = *(f16x8*)&Ars[wm * 32 + 16 + fr][ko];
        f16x8 ai0 = *(f16x8*)&Ais[wm * 32 + fr][ko];
        f16x8 ai1 = *(f16x8*)&Ais[wm * 32 + 16 + fr][ko];
        f16x8 an0 = *(f16x8*)&Ans[wm * 32 + fr][ko];
        f16x8 an1 = *(f16x8*)&Ans[wm * 32 + 16 + fr][ko];
        #pragma unroll
        for (int nf = 0; nf < 2; ++nf) {
            int brow = wn * 32 + nf * 16 + fr;
            f16x8 br = *(const f16x8*)(Bre + (size_t)brow * 64 + ko);
            f16x8 bi = *(const f16x8*)(Bim + (size_t)brow * 64 + ko);
            accr[0][nf] = __builtin_amdgcn_mfma_f32_16x16x32_f16(ar0, br, accr[0][nf], 0, 0, 0);
            accr[0][nf] = __builtin_amdgcn_mfma_f32_16x16x32_f16(an0, bi, accr[0][nf], 0, 0, 0);
            acci[0][nf] = __builtin_amdgcn_mfma_f32_16x16x32_f16(ar0, bi, acci[0][nf], 0, 0, 0);
            acci[0][nf] = __builtin_amdgcn_mfma_f32_16x16x32_f16(ai0, br, acci[0][nf], 0, 0, 0);
            accr[1][nf] = __builtin_amdgcn_mfma_f32_16x16x32_f16(ar1, br, accr[1][nf], 0, 0, 0);
            accr[1][nf] = __builtin_amdgcn_mfma_f32_16x16x32_f16(an1, bi, accr[1][nf], 0, 0, 0);
            acci[1][nf] = __builtin_amdgcn_mfma_f32_16x16x32_f16(ar1, bi, acci[1][nf], 0, 0, 0);
            acci[1][nf] = __builtin_amdgcn_mfma_f32_16x16x32_f16(ai1, br, acci[1][nf], 0, 0, 0);
        }
    }
    int rg = (lane >> 4) * 4;
    #pragma unroll
    for (int mf = 0; mf < 2; ++mf)
        #pragma unroll
        for (int nf = 0; nf < 2; ++nf) {
            int co = wn * 32 + nf * 16 + fr;
            #pragma unroll
            for (int r = 0; r < 4; ++r) {
                int mp = mt * 64 + wm * 32 + mf * 16 + rg + r;
                if (mp < 255) {
                    Or[(size_t)mp * 8192 + l * 64 + co] = (f16)accr[mf][nf][r];
                    Oi[(size_t)mp * 8192 + l * 64 + co] = (f16)acci[mf][nf][r];
                }
            }
        }
}

// ---------------- K_g4: stage 4 MFMA (64-tile, round-4 form) ----------------
__global__ __launch_bounds__(256) void k_g4(const f16* __restrict__ legT, const f16* __restrict__ OTr,
        const f16* __restrict__ OTi, f16* __restrict__ G) {
    __shared__ f16 As[64][40], Br[64][40], Bi[64][40];
    int mp = blockIdx.x, tt = blockIdx.y, tid = threadIdx.x;
    int mmv = mp - 127, am = mmv < 0 ? -mmv : mmv;
    const f16* A  = legT + (size_t)am * (256 * 128) + (size_t)(tt * 64) * 128;
    const f16* B0 = OTr + (size_t)mp * (64 * 128);
    const f16* B1 = OTi + (size_t)mp * (64 * 128);
    f32x4 acc[2][2][2];
    #pragma unroll
    for (int a = 0; a < 2; ++a)
        #pragma unroll
        for (int b = 0; b < 2; ++b)
            #pragma unroll
            for (int c = 0; c < 2; ++c) acc[a][b][c] = (f32x4){0.f, 0.f, 0.f, 0.f};
    int lane = tid & 63, wid = tid >> 6;
    int wm = wid & 1, wn = wid >> 1;
    int fr = lane & 15, g8 = (lane >> 4) * 8;
    int row = tid >> 2, k8 = (tid & 3) * 8;
    for (int kt = am >> 5; kt < 4; ++kt) {
        float4 va = *(const float4*)(A  + (size_t)row * 128 + kt * 32 + k8);
        float4 vr = *(const float4*)(B0 + (size_t)row * 128 + kt * 32 + k8);
        float4 vi = *(const float4*)(B1 + (size_t)row * 128 + kt * 32 + k8);
        __syncthreads();
        *(float4*)&As[row][k8] = va;
        *(float4*)&Br[row][k8] = vr;
        *(float4*)&Bi[row][k8] = vi;
        __syncthreads();
        f16x8 a0 = *(f16x8*)&As[wm * 32 + fr][g8];
        f16x8 a1 = *(f16x8*)&As[wm * 32 + 16 + fr][g8];
        f16x8 r0 = *(f16x8*)&Br[wn * 32 + fr][g8];
        f16x8 r1 = *(f16x8*)&Br[wn * 32 + 16 + fr][g8];
        f16x8 i0 = *(f16x8*)&Bi[wn * 32 + fr][g8];
        f16x8 i1 = *(f16x8*)&Bi[wn * 32 + 16 + fr][g8];
        acc[0][0][0] = __builtin_amdgcn_mfma_f32_16x16x32_f16(a0, r0, acc[0][0][0], 0, 0, 0);
        acc[0][0][1] = __builtin_amdgcn_mfma_f32_16x16x32_f16(a0, r1, acc[0][0][1], 0, 0, 0);
        acc[0][1][0] = __builtin_amdgcn_mfma_f32_16x16x32_f16(a1, r0, acc[0][1][0], 0, 0, 0);
        acc[0][1][1] = __builtin_amdgcn_mfma_f32_16x16x32_f16(a1, r1, acc[0][1][1], 0, 0, 0);
        acc[1][0][0] = __builtin_amdgcn_mfma_f32_16x16x32_f16(a0, i0, acc[1][0][0], 0, 0, 0);
        acc[1][0][1] = __builtin_amdgcn_mfma_f32_16x16x32_f16(a0, i1, acc[1][0][1], 0, 0, 0);
        acc[1][1][0] = __builtin_amdgcn_mfma_f32_16x16x32_f16(a1, i0, acc[1][1][0], 0, 0, 0);
        acc[1][1][1] = __builtin_amdgcn_mfma_f32_16x16x32_f16(a1, i1, acc[1][1][1], 0, 0, 0);
    }
    int rg = (lane >> 4) * 4;
    f16* gr = G + (size_t)(2 * mp) * (256 * 64);
    f16* gi = G + (size_t)(2 * mp + 1) * (256 * 64);
    #pragma unroll
    for (int mf = 0; mf < 2; ++mf)
        #pragma unroll
        for (int nf = 0; nf < 2; ++nf) {
            int c = wn * 32 + nf * 16 + fr;
            #pragma unroll
            for (int r = 0; r < 4; ++r) {
                int tl = tt * 64 + wm * 32 + mf * 16 + rg + r;
                gr[(size_t)tl * 64 + c] = (f16)acc[0][mf][nf][r];
                gi[(size_t)tl * 64 + c] = (f16)acc[1][mf][nf][r];
            }
        }
}

// ---------------- K_g5: stage 5 MFMA (64-tile, round-4 form) ----------------
__global__ __launch_bounds__(256) void k_g5(const f16* __restrict__ A5, const f16* __restrict__ GT,
                                            float* __restrict__ out) {
    __shared__ f16 As[64][40], Bs[64][40];
    int t = blockIdx.x, pt = blockIdx.y, tid = threadIdx.x;
    const f16* A = A5 + (size_t)(pt * 64) * 512;
    const f16* B = GT + (size_t)t * (64 * 512);
    f32x4 acc[2][2];
    #pragma unroll
    for (int a = 0; a < 2; ++a)
        #pragma unroll
        for (int b = 0; b < 2; ++b) acc[a][b] = (f32x4){0.f, 0.f, 0.f, 0.f};
    int lane = tid & 63, wid = tid >> 6;
    int wm = wid & 1, wn = wid >> 1;
    int fr = lane & 15, g8 = (lane >> 4) * 8;
    int row = tid >> 2, k8 = (tid & 3) * 8;
    for (int kt = 0; kt < 16; ++kt) {
        float4 va = *(const float4*)(A + (size_t)row * 512 + kt * 32 + k8);
        float4 vb = *(const float4*)(B + (size_t)row * 512 + kt * 32 + k8);
        __syncthreads();
        *(float4*)&As[row][k8] = va;
        *(float4*)&Bs[row][k8] = vb;
        __syncthreads();
        f16x8 a0 = *(f16x8*)&As[wm * 32 + fr][g8];
        f16x8 a1 = *(f16x8*)&As[wm * 32 + 16 + fr][g8];
        f16x8 b0 = *(f16x8*)&Bs[wn * 32 + fr][g8];
        f16x8 b1 = *(f16x8*)&Bs[wn * 32 + 16 + fr][g8];
        acc[0][0] = __builtin_amdgcn_mfma_f32_16x16x32_f16(a0, b0, acc[0][0], 0, 0, 0);
        acc[0][1] = __builtin_amdgcn_mfma_f32_16x16x32_f16(a0, b1, acc[0][1], 0, 0, 0);
        acc[1][0] = __builtin_amdgcn_mfma_f32_16x16x32_f16(a1, b0, acc[1][0], 0, 0, 0);
        acc[1][1] = __builtin_amdgcn_mfma_f32_16x16x32_f16(a1, b1, acc[1][1], 0, 0, 0);
    }
    int rg = (lane >> 4) * 4;
    #pragma unroll
    for (int mf = 0; mf < 2; ++mf)
        #pragma unroll
        for (int nf = 0; nf < 2; ++nf) {
            int c = wn * 32 + nf * 16 + fr;
            #pragma unroll
            for (int r = 0; r < 4; ++r) {
                int p = pt * 64 + wm * 32 + mf * 16 + rg + r;
                if (p < NPHI) out[((size_t)t * NPHI + p) * 64 + c] = acc[mf][nf][r];
            }
        }
}

extern "C" void kernel_launch(void* const* d_in, const int* in_sizes, int n_in,
                              void* d_out, int out_size, void* d_ws, size_t ws_size,
                              hipStream_t stream) {
    const float* x    = (const float*)d_in[0];
    const float* temb = (const float*)d_in[1];
    const float* Ar   = (const float*)d_in[2];
    const float* Ai   = (const float*)d_in[3];
    const float* Rr   = (const float*)d_in[4];
    const float* Ri   = (const float*)d_in[5];
    float* out = (float*)d_out;

    char* ws = (char*)d_ws;
    size_t off = 0;
    auto alloc = [&](size_t bytes) -> void* {
        void* p = ws + off;
        off = (off + bytes + 255) & ~(size_t)255;
        return p;
    };
    double* w64  = (double*)alloc(256 * 8);
    f16* legh   = (f16*)alloc((size_t)128 * 128 * 256 * 2);   // 8.39 MB
    f16* leghT  = (f16*)alloc((size_t)128 * 256 * 128 * 2);   // 8.39 MB
    f16* CS     = (f16*)alloc((size_t)2 * 128 * 512 * 2);     // 256 KB (cF | sF)
    f16* A5     = (f16*)alloc((size_t)512 * 512 * 2);         // 512 KB
    f16* Rphr   = (f16*)alloc((size_t)128 * 64 * 64 * 2);     // 1.05 MB
    f16* Rphi   = (f16*)alloc((size_t)128 * 64 * 64 * 2);
    f16* R1     = (f16*)alloc((size_t)256 * 64 * 512 * 2);    // 16.78 MB: xh -> GT
    f16* R2     = (f16*)alloc((size_t)512 * 256 * 64 * 2);    // 16.78 MB: Fw{R,I,RT,IT} -> Gk
    f16* Xhr    = (f16*)alloc((size_t)128 * 128 * 64 * 2);    // 2.1 MB
    f16* Xhi    = (f16*)alloc((size_t)128 * 128 * 64 * 2);
    f16* Or     = (f16*)alloc((size_t)255 * 128 * 64 * 2);    // 4.18 MB
    f16* Oi     = (f16*)alloc((size_t)255 * 128 * 64 * 2);
    f16* OrT    = (f16*)alloc((size_t)255 * 64 * 128 * 2);
    f16* OiT    = (f16*)alloc((size_t)255 * 64 * 128 * 2);
    if (off > ws_size) return;

    f16* xh   = R1;
    f16* GT   = R1;
    f16* FwR  = R2;
    f16* FwI  = R2 + (size_t)2097152;
    f16* FwRT = R2 + (size_t)4194304;
    f16* FwIT = R2 + (size_t)6291456;
    f16* Gk   = R2;   // rows 510,511 stale-but-finite; A5 cols 510,511 == 0
    f16* cF   = CS;
    f16* sF   = CS + (size_t)65536;

    hipLaunchKernelGGL(k_leg,      dim3(128),        dim3(256), 0, stream, legh, leghT, w64);
    hipLaunchKernelGGL(k_tables_h, dim3(1024),       dim3(256), 0, stream, CS, A5);
    hipLaunchKernelGGL(k_prep_R,   dim3(128),        dim3(256), 0, stream, Rr, Ri, Ar, Ai, temb, Rphr, Rphi);
    hipLaunchKernelGGL(k_convert,  dim3(256, 8),     dim3(256), 0, stream, x, xh);
    hipLaunchKernelGGL(k_g1,       dim3(256, 2),     dim3(256), 0, stream, xh, cF, sF, w64, FwR, FwI);
    hipLaunchKernelGGL(k_trp,      dim3(128, 4, 2),  dim3(256), 0, stream, FwR, FwRT, FwI, FwIT, 256, 64, 16384, 16384);
    hipLaunchKernelGGL(k_g2,       dim3(128, 2),     dim3(256), 0, stream, legh, FwRT, FwIT, Xhr, Xhi);
    hipLaunchKernelGGL(k_s3m,      dim3(128, 4),     dim3(256), 0, stream, Xhr, Xhi, Rphr, Rphi, Or, Oi);
    hipLaunchKernelGGL(k_trp,      dim3(255, 2, 2),  dim3(256), 0, stream, Or, OrT, Oi, OiT, 128, 64, 8192, 8192);
    hipLaunchKernelGGL(k_g4,       dim3(255, 4),     dim3(256), 0, stream, leghT, OrT, OiT, Gk);
    hipLaunchKernelGGL(k_tr16,     dim3(1, 2048),    dim3(256), 0, stream, Gk, GT, 512, 16384);
    hipLaunchKernelGGL(k_g5,       dim3(256, 8),     dim3(256), 0, stream, A5, GT, out);
}

// Round 12
// 98.300 us; speedup vs baseline: 2.9379x; 1.2694x over previous
//
#include <hip/hip_runtime.h>
#include <math.h>

#ifndef M_PI
#define M_PI 3.14159265358979323846
#endif

typedef _Float16 f16;
typedef _Float16 f16x8 __attribute__((ext_vector_type(8)));
typedef unsigned short u16x8 __attribute__((ext_vector_type(8)));
typedef float f32x4 __attribute__((ext_vector_type(4)));

#define NPHI 511
#define NM   255

// ==================== fused setup: leg | tables | prep_R | convert ==========
__device__ __forceinline__ void leg_body(char* smem, int m, int t,
        f16* __restrict__ legh, f16* __restrict__ leghT, double* __restrict__ w64) {
    float4* ct4  = (float4*)smem;            // [128]
    float4* sab4 = (float4*)(smem + 2048);   // [64]
    double* lg   = (double*)(smem + 3072);   // [256]
    if (t < 128) {
        int k0 = 2 + 2 * t, k1 = 3 + 2 * t;
        ct4[t] = make_float4((float)((2.0 * k0 - 1.0) / k0), (float)((k0 - 1.0) / (double)k0),
                             (float)((2.0 * k1 - 1.0) / k1), (float)((k1 - 1.0) / (double)k1));
    } else {
        int i = t - 128;
        if (i < 64) {
            int l0 = 2 * i, l1 = 2 * i + 1;
            float a0 = 1.f, b0 = 0.f, a1 = 1.f, b1 = 0.f;
            double dm = m;
            if (l0 >= 2) {
                double dl = l0;
                a0 = (float)sqrt((4.0 * dl * dl - 1.0) / (dl * dl - dm * dm));
                b0 = (float)sqrt(((dl - 1.0) * (dl - 1.0) - dm * dm) / (4.0 * (dl - 1.0) * (dl - 1.0) - 1.0));
            }
            if (l1 >= 2) {
                double dl = l1;
                a1 = (float)sqrt((4.0 * dl * dl - 1.0) / (dl * dl - dm * dm));
                b1 = (float)sqrt(((dl - 1.0) * (dl - 1.0) - dm * dm) / (4.0 * (dl - 1.0) * (dl - 1.0) - 1.0));
            }
            sab4[i] = make_float4(a0, b0, a1, b1);
        }
    }
    lg[t] = (t >= 1 && t <= m) ? 0.5 * log1p(0.5 / (double)t) : 0.0;
    __syncthreads();
    for (int s = 128; s > 0; s >>= 1) {
        if (t < s) lg[t] += lg[t + s];
        __syncthreads();
    }
    double sumlog = lg[0];

    const double dn = 256.0;
    double theta = M_PI * (t + 0.75) / (dn + 0.5);
    double st = sin(theta);
    double x = (1.0 - (dn - 1.0) / (8.0 * dn * dn * dn)
                    - (39.0 - 28.0 / (st * st)) / (384.0 * dn * dn * dn * dn)) * cos(theta);

#define NSTEP(C1, C2) { double pk = (double)(C1) * x * p1 - (double)(C2) * p0; p0 = p1; p1 = pk; }
    double p1 = x, pd = 1.0;
    #pragma unroll 1
    for (int it = 0; it < 2; ++it) {
        double p0 = 1.0; p1 = x;
        #pragma unroll 1
        for (int g = 0; g < 31; ++g) {
            float4 q0 = ct4[4 * g + 0], q1 = ct4[4 * g + 1];
            float4 q2 = ct4[4 * g + 2], q3 = ct4[4 * g + 3];
            NSTEP(q0.x, q0.y) NSTEP(q0.z, q0.w) NSTEP(q1.x, q1.y) NSTEP(q1.z, q1.w)
            NSTEP(q2.x, q2.y) NSTEP(q2.z, q2.w) NSTEP(q3.x, q3.y) NSTEP(q3.z, q3.w)
        }
        {
            float4 q0 = ct4[124], q1 = ct4[125], q2 = ct4[126], q3 = ct4[127];
            NSTEP(q0.x, q0.y) NSTEP(q0.z, q0.w) NSTEP(q1.x, q1.y) NSTEP(q1.z, q1.w)
            NSTEP(q2.x, q2.y) NSTEP(q2.z, q2.w) NSTEP(q3.x, q3.y)
        }
        pd = dn * (x * p1 - p0) / (x * x - 1.0);
        x -= p1 / pd;
    }
#undef NSTEP
    if (m == 0) w64[t] = 2.0 / ((1.0 - x * x) * pd * pd);

    double sx = sqrt(fmax(0.0, 1.0 - x * x));
    double prodm = exp(sumlog);
    if (m & 1) prodm = -prodm;
    double sxm = 1.0, bse = sx;
    int e = m;
    #pragma unroll
    for (int b7 = 0; b7 < 7; ++b7) { if (e & 1) sxm *= bse; bse *= bse; e >>= 1; }
    double pmm = 0.28209479177387814 * prodm * sxm;
    double pm1 = (m + 1 < 128) ? sqrt(2.0 * m + 3.0) * x * pmm : 0.0;

    f16* Lm  = legh  + (size_t)m * 32768;
    f16* LmT = leghT + (size_t)m * 32768;
    double pprev = 0.0, pcur = 0.0;
#define LSTEP(J, SA, SB) { int l = h * 8 + (J); double v; \
        if (l < m) v = 0.0; \
        else if (l == m) v = pmm; \
        else if (l == m + 1) v = pm1; \
        else v = (double)(SA) * (x * pcur - (double)(SB) * pprev); \
        if (l >= m) { pprev = pcur; pcur = v; } \
        f16 hh = (f16)v; Lm[l * 256 + t] = hh; tbuf[J] = hh; }
    #pragma unroll 1
    for (int h = 0; h < 16; ++h) {
        float4 s0 = sab4[4 * h + 0], s1 = sab4[4 * h + 1];
        float4 s2 = sab4[4 * h + 2], s3 = sab4[4 * h + 3];
        __align__(16) f16 tbuf[8];
        LSTEP(0, s0.x, s0.y) LSTEP(1, s0.z, s0.w) LSTEP(2, s1.x, s1.y) LSTEP(3, s1.z, s1.w)
        LSTEP(4, s2.x, s2.y) LSTEP(5, s2.z, s2.w) LSTEP(6, s3.x, s3.y) LSTEP(7, s3.z, s3.w)
        *(float4*)(LmT + (size_t)t * 128 + h * 8) = *(float4*)tbuf;
    }
#undef LSTEP
}

__device__ __forceinline__ void tables_body(int tid, f16* __restrict__ CS, f16* __restrict__ A5) {
    const float w0 = (float)(2.0 * M_PI / 511.0);
    if (tid < 128 * 512) {
        int m = tid >> 9, p = tid & 511;
        float cv = 0.f, sv = 0.f;
        if (p < 511) {
            int r = (p * m) % 511;
            float ang = w0 * (float)r;
            cv = cosf(ang) * w0;
            sv = -sinf(ang) * w0;
        }
        CS[tid] = (f16)cv; CS[65536 + tid] = (f16)sv;
    }
    {
        int p = tid >> 9, k = tid & 511;
        float v = 0.f;
        if (p < 511 && k < 510) {
            int mp = k >> 1, mmv = mp - 127;
            int r = (p * mmv) % 511; if (r < 0) r += 511;
            float ang = w0 * (float)r;
            v = (k & 1) ? -sinf(ang) : cosf(ang);
        }
        A5[tid] = (f16)v;
    }
}

__device__ __forceinline__ void prepR_body(char* smem, int l, int tid,
        const float* __restrict__ Rr, const float* __restrict__ Ri,
        const float* __restrict__ Ar, const float* __restrict__ Ai, const float* __restrict__ te,
        f16* __restrict__ Rphr, f16* __restrict__ Rphi) {
    float* srd = (float*)smem;
    float* sid = srd + 256;
    float tv = te[tid];
    srd[tid] = Ar[l * 256 + tid] * tv;
    sid[tid] = Ai[l * 256 + tid] * tv;
    __syncthreads();
    for (int s = 128; s > 0; s >>= 1) {
        if (tid < s) { srd[tid] += srd[tid + s]; sid[tid] += sid[tid + s]; }
        __syncthreads();
    }
    float phr = srd[0], phii = sid[0];
    const float* rr = Rr + (size_t)l * 4096;
    const float* ri = Ri + (size_t)l * 4096;
    #pragma unroll
    for (int e = 0; e < 2; ++e) {
        int base = tid * 8 + e * 2048;
        float4 r0 = *(const float4*)(rr + base), r1 = *(const float4*)(rr + base + 4);
        float4 q0 = *(const float4*)(ri + base), q1 = *(const float4*)(ri + base + 4);
        __align__(16) f16 hr[8], hi[8];
        hr[0] = (f16)(r0.x * phr - q0.x * phii); hi[0] = (f16)(r0.x * phii + q0.x * phr);
        hr[1] = (f16)(r0.y * phr - q0.y * phii); hi[1] = (f16)(r0.y * phii + q0.y * phr);
        hr[2] = (f16)(r0.z * phr - q0.z * phii); hi[2] = (f16)(r0.z * phii + q0.z * phr);
        hr[3] = (f16)(r0.w * phr - q0.w * phii); hi[3] = (f16)(r0.w * phii + q0.w * phr);
        hr[4] = (f16)(r1.x * phr - q1.x * phii); hi[4] = (f16)(r1.x * phii + q1.x * phr);
        hr[5] = (f16)(r1.y * phr - q1.y * phii); hi[5] = (f16)(r1.y * phii + q1.y * phr);
        hr[6] = (f16)(r1.z * phr - q1.z * phii); hi[6] = (f16)(r1.z * phii + q1.z * phr);
        hr[7] = (f16)(r1.w * phr - q1.w * phii); hi[7] = (f16)(r1.w * phii + q1.w * phr);
        *(float4*)(Rphr + (size_t)l * 4096 + base) = *(float4*)hr;
        *(float4*)(Rphi + (size_t)l * 4096 + base) = *(float4*)hi;
    }
}

__device__ __forceinline__ void convert_body(char* smem, int t, int pt, int tid,
        const float* __restrict__ x, f16* __restrict__ xh) {
    float (*Ls)[68] = (float(*)[68])smem;
    int p0 = pt * 64;
    const float* xb = x + (size_t)t * (NPHI * 64);
    #pragma unroll
    for (int e = 0; e < 4; ++e) {
        int idx = tid + e * 256;
        int row = idx >> 4, c4 = (idx & 15) * 4;
        int p = p0 + row;
        float4 v = make_float4(0.f, 0.f, 0.f, 0.f);
        if (p < NPHI) v = *(const float4*)(xb + (size_t)p * 64 + c4);
        *(float4*)&Ls[row][c4] = v;
    }
    __syncthreads();
    #pragma unroll
    for (int e = 0; e < 2; ++e) {
        int idx = tid + e * 256;
        int c = idx >> 3, r8 = (idx & 7) * 8;
        __align__(16) f16 tmp[8];
        #pragma unroll
        for (int j = 0; j < 8; ++j) tmp[j] = (f16)Ls[r8 + j][c];
        *(float4*)(xh + (size_t)t * 32768 + (size_t)c * 512 + p0 + r8) = *(float4*)tmp;
    }
}

__global__ __launch_bounds__(256) void k_setup(
        f16* __restrict__ legh, f16* __restrict__ leghT, double* __restrict__ w64,
        f16* __restrict__ CS, f16* __restrict__ A5,
        const float* __restrict__ Rr, const float* __restrict__ Ri,
        const float* __restrict__ Ar, const float* __restrict__ Ai, const float* __restrict__ te,
        f16* __restrict__ Rphr, f16* __restrict__ Rphi,
        const float* __restrict__ x, f16* __restrict__ xh) {
    __shared__ __align__(16) char smem[64 * 68 * 4];
    int bid = blockIdx.x, tid = threadIdx.x;
    if (bid < 128) {
        leg_body(smem, bid, tid, legh, leghT, w64);
    } else if (bid < 1152) {
        tables_body((bid - 128) * 256 + tid, CS, A5);
    } else if (bid < 1280) {
        prepR_body(smem, bid - 1152, tid, Rr, Ri, Ar, Ai, te, Rphr, Rphi);
    } else {
        int cb = bid - 1280;
        convert_body(smem, cb >> 3, cb & 7, tid, x, xh);
    }
}

// ==================== K_g1: stage 1 MFMA (unchanged round-4 form) ===========
__global__ __launch_bounds__(256) void k_g1(const f16* __restrict__ xh, const f16* __restrict__ cF,
        const f16* __restrict__ sF, const double* __restrict__ w64,
        f16* __restrict__ FwR, f16* __restrict__ FwI) {
    __shared__ f16 Ac[64][40], An[64][40], Bs[64][40];
    int t = blockIdx.x, mt = blockIdx.y, tid = threadIdx.x;
    const f16* A0 = cF + (size_t)(mt * 64) * 512;
    const f16* A1 = sF + (size_t)(mt * 64) * 512;
    const f16* B  = xh + (size_t)t * (64 * 512);
    f32x4 acc[2][2][2];
    #pragma unroll
    for (int a = 0; a < 2; ++a)
        #pragma unroll
        for (int b = 0; b < 2; ++b)
            #pragma unroll
            for (int c = 0; c < 2; ++c) acc[a][b][c] = (f32x4){0.f, 0.f, 0.f, 0.f};
    int lane = tid & 63, wid = tid >> 6;
    int wm = wid & 1, wn = wid >> 1;
    int fr = lane & 15, g8 = (lane >> 4) * 8;
    int row = tid >> 2, k8 = (tid & 3) * 8;
    for (int kt = 0; kt < 16; ++kt) {
        float4 va = *(const float4*)(A0 + (size_t)row * 512 + kt * 32 + k8);
        float4 vn = *(const float4*)(A1 + (size_t)row * 512 + kt * 32 + k8);
        float4 vb = *(const float4*)(B  + (size_t)row * 512 + kt * 32 + k8);
        __syncthreads();
        *(float4*)&Ac[row][k8] = va;
        *(float4*)&An[row][k8] = vn;
        *(float4*)&Bs[row][k8] = vb;
        __syncthreads();
        f16x8 b0 = *(f16x8*)&Bs[wn * 32 + fr][g8];
        f16x8 b1 = *(f16x8*)&Bs[wn * 32 + 16 + fr][g8];
        f16x8 a0 = *(f16x8*)&Ac[wm * 32 + fr][g8];
        f16x8 a1 = *(f16x8*)&Ac[wm * 32 + 16 + fr][g8];
        f16x8 s0 = *(f16x8*)&An[wm * 32 + fr][g8];
        f16x8 s1 = *(f16x8*)&An[wm * 32 + 16 + fr][g8];
        acc[0][0][0] = __builtin_amdgcn_mfma_f32_16x16x32_f16(a0, b0, acc[0][0][0], 0, 0, 0);
        acc[0][0][1] = __builtin_amdgcn_mfma_f32_16x16x32_f16(a0, b1, acc[0][0][1], 0, 0, 0);
        acc[0][1][0] = __builtin_amdgcn_mfma_f32_16x16x32_f16(a1, b0, acc[0][1][0], 0, 0, 0);
        acc[0][1][1] = __builtin_amdgcn_mfma_f32_16x16x32_f16(a1, b1, acc[0][1][1], 0, 0, 0);
        acc[1][0][0] = __builtin_amdgcn_mfma_f32_16x16x32_f16(s0, b0, acc[1][0][0], 0, 0, 0);
        acc[1][0][1] = __builtin_amdgcn_mfma_f32_16x16x32_f16(s0, b1, acc[1][0][1], 0, 0, 0);
        acc[1][1][0] = __builtin_amdgcn_mfma_f32_16x16x32_f16(s1, b0, acc[1][1][0], 0, 0, 0);
        acc[1][1][1] = __builtin_amdgcn_mfma_f32_16x16x32_f16(s1, b1, acc[1][1][1], 0, 0, 0);
    }
    float wf = (float)w64[t];
    int rg = (lane >> 4) * 4;
    #pragma unroll
    for (int mf = 0; mf < 2; ++mf)
        #pragma unroll
        for (int nf = 0; nf < 2; ++nf) {
            int c = wn * 32 + nf * 16 + fr;
            #pragma unroll
            for (int r = 0; r < 4; ++r) {
                int m = mt * 64 + wm * 32 + mf * 16 + rg + r;
                FwR[((size_t)m * 256 + t) * 64 + c] = (f16)(acc[0][mf][nf][r] * wf);
                FwI[((size_t)m * 256 + t) * 64 + c] = (f16)(acc[1][mf][nf][r] * wf);
            }
        }
}

// ==================== K_g2: B consumed in [t][c] layout (no pre-transpose) ==
__global__ __launch_bounds__(256) void k_g2(const f16* __restrict__ legh, const f16* __restrict__ FwR,
        const f16* __restrict__ FwI, f16* __restrict__ Xhr, f16* __restrict__ Xhi) {
    __shared__ f16 As[64][40];
    __shared__ f16 Brs[32][68], Bis[32][68];
    int m = blockIdx.x, lt = blockIdx.y, tid = threadIdx.x;
    const f16* A  = legh + (size_t)m * (128 * 256) + (size_t)(lt * 64) * 256;
    const f16* B0 = FwR + (size_t)m * 16384;   // [t][c]
    const f16* B1 = FwI + (size_t)m * 16384;
    f32x4 acc[2][2][2];
    #pragma unroll
    for (int a = 0; a < 2; ++a)
        #pragma unroll
        for (int b = 0; b < 2; ++b)
            #pragma unroll
            for (int c = 0; c < 2; ++c) acc[a][b][c] = (f32x4){0.f, 0.f, 0.f, 0.f};
    int lane = tid & 63, wid = tid >> 6;
    int wm = wid & 1, wn = wid >> 1;
    int fr = lane & 15, g8 = (lane >> 4) * 8;
    int row = tid >> 2, k8 = (tid & 3) * 8;
    int btr = tid >> 3, bc8 = (tid & 7) * 8;
    for (int kt = 0; kt < 8; ++kt) {
        float4 va = *(const float4*)(A  + (size_t)row * 256 + kt * 32 + k8);
        float4 vr = *(const float4*)(B0 + (size_t)(kt * 32 + btr) * 64 + bc8);
        float4 vi = *(const float4*)(B1 + (size_t)(kt * 32 + btr) * 64 + bc8);
        __syncthreads();
        *(float4*)&As[row][k8] = va;
        *(float4*)&Brs[btr][bc8] = vr;
        *(float4*)&Bis[btr][bc8] = vi;
        __syncthreads();
        f16x8 a0 = *(f16x8*)&As[wm * 32 + fr][g8];
        f16x8 a1 = *(f16x8*)&As[wm * 32 + 16 + fr][g8];
        f16x8 r0, r1, i0, i1;
        #pragma unroll
        for (int j = 0; j < 8; ++j) {
            r0[j] = Brs[g8 + j][wn * 32 + fr];
            r1[j] = Brs[g8 + j][wn * 32 + 16 + fr];
            i0[j] = Bis[g8 + j][wn * 32 + fr];
            i1[j] = Bis[g8 + j][wn * 32 + 16 + fr];
        }
        acc[0][0][0] = __builtin_amdgcn_mfma_f32_16x16x32_f16(a0, r0, acc[0][0][0], 0, 0, 0);
        acc[0][0][1] = __builtin_amdgcn_mfma_f32_16x16x32_f16(a0, r1, acc[0][0][1], 0, 0, 0);
        acc[0][1][0] = __builtin_amdgcn_mfma_f32_16x16x32_f16(a1, r0, acc[0][1][0], 0, 0, 0);
        acc[0][1][1] = __builtin_amdgcn_mfma_f32_16x16x32_f16(a1, r1, acc[0][1][1], 0, 0, 0);
        acc[1][0][0] = __builtin_amdgcn_mfma_f32_16x16x32_f16(a0, i0, acc[1][0][0], 0, 0, 0);
        acc[1][0][1] = __builtin_amdgcn_mfma_f32_16x16x32_f16(a0, i1, acc[1][0][1], 0, 0, 0);
        acc[1][1][0] = __builtin_amdgcn_mfma_f32_16x16x32_f16(a1, i0, acc[1][1][0], 0, 0, 0);
        acc[1][1][1] = __builtin_amdgcn_mfma_f32_16x16x32_f16(a1, i1, acc[1][1][1], 0, 0, 0);
    }
    int rg = (lane >> 4) * 4;
    #pragma unroll
    for (int mf = 0; mf < 2; ++mf)
        #pragma unroll
        for (int nf = 0; nf < 2; ++nf) {
            int c = wn * 32 + nf * 16 + fr;
            #pragma unroll
            for (int r = 0; r < 4; ++r) {
                int l = lt * 64 + wm * 32 + mf * 16 + rg + r;
                Xhr[(size_t)m * 8192 + l * 64 + c] = (f16)acc[0][mf][nf][r];
                Xhi[(size_t)m * 8192 + l * 64 + c] = (f16)acc[1][mf][nf][r];
            }
        }
}

// ==================== K_s3m: stage 3 MFMA (unchanged) =======================
__global__ __launch_bounds__(256) void k_s3m(const f16* __restrict__ Xhr, const f16* __restrict__ Xhi,
        const f16* __restrict__ Rphr, const f16* __restrict__ Rphi,
        f16* __restrict__ Or, f16* __restrict__ Oi) {
    __shared__ f16 Ars[64][72], Ais[64][72], Ans[64][72];
    int l = blockIdx.x, mt = blockIdx.y, tid = threadIdx.x;
    {
        int arow = tid >> 2;
        int mp = mt * 64 + arow;
        int mmv = mp - 127, am = mmv < 0 ? -mmv : mmv;
        unsigned short cj = (mmv < 0) ? 0x8000 : 0;
        u16x8 cjv = {cj, cj, cj, cj, cj, cj, cj, cj};
        u16x8 ngv = {0x8000, 0x8000, 0x8000, 0x8000, 0x8000, 0x8000, 0x8000, 0x8000};
        #pragma unroll
        for (int e = 0; e < 2; ++e) {
            int ci8 = (tid & 3) * 8 + e * 32;
            u16x8 vr = {0, 0, 0, 0, 0, 0, 0, 0};
            u16x8 vi = {0, 0, 0, 0, 0, 0, 0, 0};
            if (mp < 255) {
                vr = *(const u16x8*)(Xhr + (size_t)am * 8192 + l * 64 + ci8);
                vi = *(const u16x8*)(Xhi + (size_t)am * 8192 + l * 64 + ci8);
            }
            u16x8 vic = vi ^ cjv;
            u16x8 vin = vic ^ ngv;
            *(u16x8*)&Ars[arow][ci8] = vr;
            *(u16x8*)&Ais[arow][ci8] = vic;
            *(u16x8*)&Ans[arow][ci8] = vin;
        }
    }
    __syncthreads();
    int lane = tid & 63, wid = tid >> 6;
    int wm = wid & 1, wn = wid >> 1;
    int fr = lane & 15, g8 = (lane >> 4) * 8;
    const f16* Bre = Rphr + (size_t)l * 4096;
    const f16* Bim = Rphi + (size_t)l * 4096;
    f32x4 accr[2][2], acci[2][2];
    #pragma unroll
    for (int a = 0; a < 2; ++a)
        #pragma unroll
        for (int b = 0; b < 2; ++b) { accr[a][b] = (f32x4){0.f,0.f,0.f,0.f}; acci[a][b] = (f32x4){0.f,0.f,0.f,0.f}; }
    #pragma unroll
    for (int ks = 0; ks < 2; ++ks) {
        int ko = ks * 32 + g8;
        f16x8 ar0 = *(f16x8*)&Ars[wm * 32 + fr][ko];
        f16x8 ar1 = *(f16x8*)&Ars[wm * 32 + 16 + fr][ko];
        f16x8 ai0 = *(f16x8*)&Ais[wm * 32 + fr][ko];
        f16x8 ai1 = *(f16x8*)&Ais[wm * 32 + 16 + fr][ko];
        f16x8 an0 = *(f16x8*)&Ans[wm * 32 + fr][ko];
        f16x8 an1 = *(f16x8*)&Ans[wm * 32 + 16 + fr][ko];
        #pragma unroll
        for (int nf = 0; nf < 2; ++nf) {
            int brow = wn * 32 + nf * 16 + fr;
            f16x8 br = *(const f16x8*)(Bre + (size_t)brow * 64 + ko);
            f16x8 bi = *(const f16x8*)(Bim + (size_t)brow * 64 + ko);
            accr[0][nf] = __builtin_amdgcn_mfma_f32_16x16x32_f16(ar0, br, accr[0][nf], 0, 0, 0);
            accr[0][nf] = __builtin_amdgcn_mfma_f32_16x16x32_f16(an0, bi, accr[0][nf], 0, 0, 0);
            acci[0][nf] = __builtin_amdgcn_mfma_f32_16x16x32_f16(ar0, bi, acci[0][nf], 0, 0, 0);
            acci[0][nf] = __builtin_amdgcn_mfma_f32_16x16x32_f16(ai0, br, acci[0][nf], 0, 0, 0);
            accr[1][nf] = __builtin_amdgcn_mfma_f32_16x16x32_f16(ar1, br, accr[1][nf], 0, 0, 0);
            accr[1][nf] = __builtin_amdgcn_mfma_f32_16x16x32_f16(an1, bi, accr[1][nf], 0, 0, 0);
            acci[1][nf] = __builtin_amdgcn_mfma_f32_16x16x32_f16(ar1, bi, acci[1][nf], 0, 0, 0);
            acci[1][nf] = __builtin_amdgcn_mfma_f32_16x16x32_f16(ai1, br, acci[1][nf], 0, 0, 0);
        }
    }
    int rg = (lane >> 4) * 4;
    #pragma unroll
    for (int mf = 0; mf < 2; ++mf)
        #pragma unroll
        for (int nf = 0; nf < 2; ++nf) {
            int co = wn * 32 + nf * 16 + fr;
            #pragma unroll
            for (int r = 0; r < 4; ++r) {
                int mp = mt * 64 + wm * 32 + mf * 16 + rg + r;
                if (mp < 255) {
                    Or[(size_t)mp * 8192 + l * 64 + co] = (f16)accr[mf][nf][r];
                    Oi[(size_t)mp * 8192 + l * 64 + co] = (f16)acci[mf][nf][r];
                }
            }
        }
}

// ==================== K_g4: B consumed in [l][c] layout (no pre-transpose) ==
__global__ __launch_bounds__(256) void k_g4(const f16* __restrict__ legT, const f16* __restrict__ Or,
        const f16* __restrict__ Oi, f16* __restrict__ G) {
    __shared__ f16 As[64][40];
    __shared__ f16 Brs[32][68], Bis[32][68];
    int mp = blockIdx.x, tt = blockIdx.y, tid = threadIdx.x;
    int mmv = mp - 127, am = mmv < 0 ? -mmv : mmv;
    const f16* A  = legT + (size_t)am * (256 * 128) + (size_t)(tt * 64) * 128;
    const f16* B0 = Or + (size_t)mp * 8192;   // [l][c]
    const f16* B1 = Oi + (size_t)mp * 8192;
    f32x4 acc[2][2][2];
    #pragma unroll
    for (int a = 0; a < 2; ++a)
        #pragma unroll
        for (int b = 0; b < 2; ++b)
            #pragma unroll
            for (int c = 0; c < 2; ++c) acc[a][b][c] = (f32x4){0.f, 0.f, 0.f, 0.f};
    int lane = tid & 63, wid = tid >> 6;
    int wm = wid & 1, wn = wid >> 1;
    int fr = lane & 15, g8 = (lane >> 4) * 8;
    int row = tid >> 2, k8 = (tid & 3) * 8;
    int btr = tid >> 3, bc8 = (tid & 7) * 8;
    for (int kt = am >> 5; kt < 4; ++kt) {
        float4 va = *(const float4*)(A  + (size_t)row * 128 + kt * 32 + k8);
        float4 vr = *(const float4*)(B0 + (size_t)(kt * 32 + btr) * 64 + bc8);
        float4 vi = *(const float4*)(B1 + (size_t)(kt * 32 + btr) * 64 + bc8);
        __syncthreads();
        *(float4*)&As[row][k8] = va;
        *(float4*)&Brs[btr][bc8] = vr;
        *(float4*)&Bis[btr][bc8] = vi;
        __syncthreads();
        f16x8 a0 = *(f16x8*)&As[wm * 32 + fr][g8];
        f16x8 a1 = *(f16x8*)&As[wm * 32 + 16 + fr][g8];
        f16x8 r0, r1, i0, i1;
        #pragma unroll
        for (int j = 0; j < 8; ++j) {
            r0[j] = Brs[g8 + j][wn * 32 + fr];
            r1[j] = Brs[g8 + j][wn * 32 + 16 + fr];
            i0[j] = Bis[g8 + j][wn * 32 + fr];
            i1[j] = Bis[g8 + j][wn * 32 + 16 + fr];
        }
        acc[0][0][0] = __builtin_amdgcn_mfma_f32_16x16x32_f16(a0, r0, acc[0][0][0], 0, 0, 0);
        acc[0][0][1] = __builtin_amdgcn_mfma_f32_16x16x32_f16(a0, r1, acc[0][0][1], 0, 0, 0);
        acc[0][1][0] = __builtin_amdgcn_mfma_f32_16x16x32_f16(a1, r0, acc[0][1][0], 0, 0, 0);
        acc[0][1][1] = __builtin_amdgcn_mfma_f32_16x16x32_f16(a1, r1, acc[0][1][1], 0, 0, 0);
        acc[1][0][0] = __builtin_amdgcn_mfma_f32_16x16x32_f16(a0, i0, acc[1][0][0], 0, 0, 0);
        acc[1][0][1] = __builtin_amdgcn_mfma_f32_16x16x32_f16(a0, i1, acc[1][0][1], 0, 0, 0);
        acc[1][1][0] = __builtin_amdgcn_mfma_f32_16x16x32_f16(a1, i0, acc[1][1][0], 0, 0, 0);
        acc[1][1][1] = __builtin_amdgcn_mfma_f32_16x16x32_f16(a1, i1, acc[1][1][1], 0, 0, 0);
    }
    int rg = (lane >> 4) * 4;
    f16* gr = G + (size_t)(2 * mp) * (256 * 64);
    f16* gi = G + (size_t)(2 * mp + 1) * (256 * 64);
    #pragma unroll
    for (int mf = 0; mf < 2; ++mf)
        #pragma unroll
        for (int nf = 0; nf < 2; ++nf) {
            int c = wn * 32 + nf * 16 + fr;
            #pragma unroll
            for (int r = 0; r < 4; ++r) {
                int tl = tt * 64 + wm * 32 + mf * 16 + rg + r;
                gr[(size_t)tl * 64 + c] = (f16)acc[0][mf][nf][r];
                gi[(size_t)tl * 64 + c] = (f16)acc[1][mf][nf][r];
            }
        }
}

// ==================== K_g5: B consumed in [k][t][c] layout (no transpose) ===
__global__ __launch_bounds__(256) void k_g5(const f16* __restrict__ A5, const f16* __restrict__ Gk,
                                            float* __restrict__ out) {
    __shared__ f16 As[64][40];
    __shared__ f16 Bs2[32][68];
    int t = blockIdx.x, pt = blockIdx.y, tid = threadIdx.x;
    const f16* A = A5 + (size_t)(pt * 64) * 512;
    f32x4 acc[2][2];
    #pragma unroll
    for (int a = 0; a < 2; ++a)
        #pragma unroll
        for (int b = 0; b < 2; ++b) acc[a][b] = (f32x4){0.f, 0.f, 0.f, 0.f};
    int lane = tid & 63, wid = tid >> 6;
    int wm = wid & 1, wn = wid >> 1;
    int fr = lane & 15, g8 = (lane >> 4) * 8;
    int row = tid >> 2, k8 = (tid & 3) * 8;
    int btr = tid >> 3, bc8 = (tid & 7) * 8;
    for (int kt = 0; kt < 16; ++kt) {
        float4 va = *(const float4*)(A + (size_t)row * 512 + kt * 32 + k8);
        float4 vb = *(const float4*)(Gk + (size_t)(kt * 32 + btr) * 16384 + t * 64 + bc8);
        __syncthreads();
        *(float4*)&As[row][k8] = va;
        *(float4*)&Bs2[btr][bc8] = vb;
        __syncthreads();
        f16x8 a0 = *(f16x8*)&As[wm * 32 + fr][g8];
        f16x8 a1 = *(f16x8*)&As[wm * 32 + 16 + fr][g8];
        f16x8 b0, b1;
        #pragma unroll
        for (int j = 0; j < 8; ++j) {
            b0[j] = Bs2[g8 + j][wn * 32 + fr];
            b1[j] = Bs2[g8 + j][wn * 32 + 16 + fr];
        }
        acc[0][0] = __builtin_amdgcn_mfma_f32_16x16x32_f16(a0, b0, acc[0][0], 0, 0, 0);
        acc[0][1] = __builtin_amdgcn_mfma_f32_16x16x32_f16(a0, b1, acc[0][1], 0, 0, 0);
        acc[1][0] = __builtin_amdgcn_mfma_f32_16x16x32_f16(a1, b0, acc[1][0], 0, 0, 0);
        acc[1][1] = __builtin_amdgcn_mfma_f32_16x16x32_f16(a1, b1, acc[1][1], 0, 0, 0);
    }
    int rg = (lane >> 4) * 4;
    #pragma unroll
    for (int mf = 0; mf < 2; ++mf)
        #pragma unroll
        for (int nf = 0; nf < 2; ++nf) {
            int c = wn * 32 + nf * 16 + fr;
            #pragma unroll
            for (int r = 0; r < 4; ++r) {
                int p = pt * 64 + wm * 32 + mf * 16 + rg + r;
                if (p < NPHI) out[((size_t)t * NPHI + p) * 64 + c] = acc[mf][nf][r];
            }
        }
}

extern "C" void kernel_launch(void* const* d_in, const int* in_sizes, int n_in,
                              void* d_out, int out_size, void* d_ws, size_t ws_size,
                              hipStream_t stream) {
    const float* x    = (const float*)d_in[0];
    const float* temb = (const float*)d_in[1];
    const float* Ar   = (const float*)d_in[2];
    const float* Ai   = (const float*)d_in[3];
    const float* Rr   = (const float*)d_in[4];
    const float* Ri   = (const float*)d_in[5];
    float* out = (float*)d_out;

    char* ws = (char*)d_ws;
    size_t off = 0;
    auto alloc = [&](size_t bytes) -> void* {
        void* p = ws + off;
        off = (off + bytes + 255) & ~(size_t)255;
        return p;
    };
    double* w64  = (double*)alloc(256 * 8);
    f16* legh   = (f16*)alloc((size_t)128 * 128 * 256 * 2);   // 8.39 MB
    f16* leghT  = (f16*)alloc((size_t)128 * 256 * 128 * 2);   // 8.39 MB
    f16* CS     = (f16*)alloc((size_t)2 * 128 * 512 * 2);     // 256 KB
    f16* A5     = (f16*)alloc((size_t)512 * 512 * 2);         // 512 KB
    f16* Rphr   = (f16*)alloc((size_t)128 * 64 * 64 * 2);     // 1.05 MB
    f16* Rphi   = (f16*)alloc((size_t)128 * 64 * 64 * 2);
    f16* R1     = (f16*)alloc((size_t)256 * 64 * 512 * 2);    // 16.78 MB: xh -> Or/Oi
    f16* R2     = (f16*)alloc((size_t)512 * 256 * 64 * 2);    // 16.78 MB: FwR/FwI/Xh -> Gk
    if (off > ws_size) return;

    f16* xh  = R1;                          // dead after k_g1
    f16* Or  = R1;                          // written by k_s3m
    f16* Oi  = R1 + (size_t)2097152;
    f16* FwR = R2;                          // written by k_g1, read by k_g2
    f16* FwI = R2 + (size_t)2097152;
    f16* Xhr = R2 + (size_t)4194304;        // written by k_g2 (does not alias Fw)
    f16* Xhi = R2 + (size_t)6291456;
    f16* Gk  = R2;                          // k_g4 output; rows 510,511 stale-but-finite, A5 cols 510,511 == 0
    f16* cF  = CS;
    f16* sF  = CS + (size_t)65536;

    hipLaunchKernelGGL(k_setup, dim3(3328),     dim3(256), 0, stream,
                       legh, leghT, w64, CS, A5, Rr, Ri, Ar, Ai, temb, Rphr, Rphi, x, xh);
    hipLaunchKernelGGL(k_g1,    dim3(256, 2),   dim3(256), 0, stream, xh, cF, sF, w64, FwR, FwI);
    hipLaunchKernelGGL(k_g2,    dim3(128, 2),   dim3(256), 0, stream, legh, FwR, FwI, Xhr, Xhi);
    hipLaunchKernelGGL(k_s3m,   dim3(128, 4),   dim3(256), 0, stream, Xhr, Xhi, Rphr, Rphi, Or, Oi);
    hipLaunchKernelGGL(k_g4,    dim3(255, 4),   dim3(256), 0, stream, leghT, Or, Oi, Gk);
    hipLaunchKernelGGL(k_g5,    dim3(256, 8),   dim3(256), 0, stream, A5, Gk, out);
}

// Round 13
// 96.654 us; speedup vs baseline: 2.9880x; 1.0170x over previous
//
#include <hip/hip_runtime.h>
#include <math.h>

#ifndef M_PI
#define M_PI 3.14159265358979323846
#endif

typedef _Float16 f16;
typedef _Float16 f16x8 __attribute__((ext_vector_type(8)));
typedef unsigned short u16x8 __attribute__((ext_vector_type(8)));
typedef float f32x4 __attribute__((ext_vector_type(4)));

#define NPHI 511
#define NM   255

// ==================== fused setup: leg | tables | prep_R | convert ==========
__device__ __forceinline__ void leg_body(char* smem, int m, int t,
        f16* __restrict__ legh, f16* __restrict__ leghT, double* __restrict__ w64) {
    float4* ct4  = (float4*)smem;            // [128]
    float4* sab4 = (float4*)(smem + 2048);   // [64]
    double* lg   = (double*)(smem + 3072);   // [256]
    if (t < 128) {
        int k0 = 2 + 2 * t, k1 = 3 + 2 * t;
        ct4[t] = make_float4((float)((2.0 * k0 - 1.0) / k0), (float)((k0 - 1.0) / (double)k0),
                             (float)((2.0 * k1 - 1.0) / k1), (float)((k1 - 1.0) / (double)k1));
    } else {
        int i = t - 128;
        if (i < 64) {
            int l0 = 2 * i, l1 = 2 * i + 1;
            float a0 = 1.f, b0 = 0.f, a1 = 1.f, b1 = 0.f;
            double dm = m;
            if (l0 >= 2) {
                double dl = l0;
                a0 = (float)sqrt((4.0 * dl * dl - 1.0) / (dl * dl - dm * dm));
                b0 = (float)sqrt(((dl - 1.0) * (dl - 1.0) - dm * dm) / (4.0 * (dl - 1.0) * (dl - 1.0) - 1.0));
            }
            if (l1 >= 2) {
                double dl = l1;
                a1 = (float)sqrt((4.0 * dl * dl - 1.0) / (dl * dl - dm * dm));
                b1 = (float)sqrt(((dl - 1.0) * (dl - 1.0) - dm * dm) / (4.0 * (dl - 1.0) * (dl - 1.0) - 1.0));
            }
            sab4[i] = make_float4(a0, b0, a1, b1);
        }
    }
    lg[t] = (t >= 1 && t <= m) ? 0.5 * log1p(0.5 / (double)t) : 0.0;
    __syncthreads();
    for (int s = 128; s > 0; s >>= 1) {
        if (t < s) lg[t] += lg[t + s];
        __syncthreads();
    }
    double sumlog = lg[0];

    const double dn = 256.0;
    double theta = M_PI * (t + 0.75) / (dn + 0.5);
    double st = sin(theta);
    double x = (1.0 - (dn - 1.0) / (8.0 * dn * dn * dn)
                    - (39.0 - 28.0 / (st * st)) / (384.0 * dn * dn * dn * dn)) * cos(theta);

#define NSTEP(C1, C2) { double pk = (double)(C1) * x * p1 - (double)(C2) * p0; p0 = p1; p1 = pk; }
    double p1 = x, pd = 1.0;
    #pragma unroll 1
    for (int it = 0; it < 2; ++it) {
        double p0 = 1.0; p1 = x;
        #pragma unroll 1
        for (int g = 0; g < 31; ++g) {
            float4 q0 = ct4[4 * g + 0], q1 = ct4[4 * g + 1];
            float4 q2 = ct4[4 * g + 2], q3 = ct4[4 * g + 3];
            NSTEP(q0.x, q0.y) NSTEP(q0.z, q0.w) NSTEP(q1.x, q1.y) NSTEP(q1.z, q1.w)
            NSTEP(q2.x, q2.y) NSTEP(q2.z, q2.w) NSTEP(q3.x, q3.y) NSTEP(q3.z, q3.w)
        }
        {
            float4 q0 = ct4[124], q1 = ct4[125], q2 = ct4[126], q3 = ct4[127];
            NSTEP(q0.x, q0.y) NSTEP(q0.z, q0.w) NSTEP(q1.x, q1.y) NSTEP(q1.z, q1.w)
            NSTEP(q2.x, q2.y) NSTEP(q2.z, q2.w) NSTEP(q3.x, q3.y)
        }
        pd = dn * (x * p1 - p0) / (x * x - 1.0);
        x -= p1 / pd;
    }
#undef NSTEP
    if (m == 0) w64[t] = 2.0 / ((1.0 - x * x) * pd * pd);

    double sx = sqrt(fmax(0.0, 1.0 - x * x));
    double prodm = exp(sumlog);
    if (m & 1) prodm = -prodm;
    double sxm = 1.0, bse = sx;
    int e = m;
    #pragma unroll
    for (int b7 = 0; b7 < 7; ++b7) { if (e & 1) sxm *= bse; bse *= bse; e >>= 1; }
    double pmm = 0.28209479177387814 * prodm * sxm;
    double pm1 = (m + 1 < 128) ? sqrt(2.0 * m + 3.0) * x * pmm : 0.0;

    f16* Lm  = legh  + (size_t)m * 32768;
    f16* LmT = leghT + (size_t)m * 32768;
    double pprev = 0.0, pcur = 0.0;
#define LSTEP(J, SA, SB) { int l = h * 8 + (J); double v; \
        if (l < m) v = 0.0; \
        else if (l == m) v = pmm; \
        else if (l == m + 1) v = pm1; \
        else v = (double)(SA) * (x * pcur - (double)(SB) * pprev); \
        if (l >= m) { pprev = pcur; pcur = v; } \
        f16 hh = (f16)v; Lm[l * 256 + t] = hh; tbuf[J] = hh; }
    #pragma unroll 1
    for (int h = 0; h < 16; ++h) {
        float4 s0 = sab4[4 * h + 0], s1 = sab4[4 * h + 1];
        float4 s2 = sab4[4 * h + 2], s3 = sab4[4 * h + 3];
        __align__(16) f16 tbuf[8];
        LSTEP(0, s0.x, s0.y) LSTEP(1, s0.z, s0.w) LSTEP(2, s1.x, s1.y) LSTEP(3, s1.z, s1.w)
        LSTEP(4, s2.x, s2.y) LSTEP(5, s2.z, s2.w) LSTEP(6, s3.x, s3.y) LSTEP(7, s3.z, s3.w)
        *(float4*)(LmT + (size_t)t * 128 + h * 8) = *(float4*)tbuf;
    }
#undef LSTEP
}

__device__ __forceinline__ void tables_body(int tid, f16* __restrict__ CS, f16* __restrict__ A5) {
    const float w0 = (float)(2.0 * M_PI / 511.0);
    if (tid < 128 * 512) {
        int m = tid >> 9, p = tid & 511;
        float cv = 0.f, sv = 0.f;
        if (p < 511) {
            int r = (p * m) % 511;
            float ang = w0 * (float)r;
            cv = cosf(ang) * w0;
            sv = -sinf(ang) * w0;
        }
        CS[tid] = (f16)cv; CS[65536 + tid] = (f16)sv;
    }
    {
        int p = tid >> 9, k = tid & 511;
        float v = 0.f;
        if (p < 511 && k < 510) {
            int mp = k >> 1, mmv = mp - 127;
            int r = (p * mmv) % 511; if (r < 0) r += 511;
            float ang = w0 * (float)r;
            v = (k & 1) ? -sinf(ang) : cosf(ang);
        }
        A5[tid] = (f16)v;
    }
}

__device__ __forceinline__ void prepR_body(char* smem, int l, int tid,
        const float* __restrict__ Rr, const float* __restrict__ Ri,
        const float* __restrict__ Ar, const float* __restrict__ Ai, const float* __restrict__ te,
        f16* __restrict__ Rphr, f16* __restrict__ Rphi) {
    float* srd = (float*)smem;
    float* sid = srd + 256;
    float tv = te[tid];
    srd[tid] = Ar[l * 256 + tid] * tv;
    sid[tid] = Ai[l * 256 + tid] * tv;
    __syncthreads();
    for (int s = 128; s > 0; s >>= 1) {
        if (tid < s) { srd[tid] += srd[tid + s]; sid[tid] += sid[tid + s]; }
        __syncthreads();
    }
    float phr = srd[0], phii = sid[0];
    const float* rr = Rr + (size_t)l * 4096;
    const float* ri = Ri + (size_t)l * 4096;
    #pragma unroll
    for (int e = 0; e < 2; ++e) {
        int base = tid * 8 + e * 2048;
        float4 r0 = *(const float4*)(rr + base), r1 = *(const float4*)(rr + base + 4);
        float4 q0 = *(const float4*)(ri + base), q1 = *(const float4*)(ri + base + 4);
        __align__(16) f16 hr[8], hi[8];
        hr[0] = (f16)(r0.x * phr - q0.x * phii); hi[0] = (f16)(r0.x * phii + q0.x * phr);
        hr[1] = (f16)(r0.y * phr - q0.y * phii); hi[1] = (f16)(r0.y * phii + q0.y * phr);
        hr[2] = (f16)(r0.z * phr - q0.z * phii); hi[2] = (f16)(r0.z * phii + q0.z * phr);
        hr[3] = (f16)(r0.w * phr - q0.w * phii); hi[3] = (f16)(r0.w * phii + q0.w * phr);
        hr[4] = (f16)(r1.x * phr - q1.x * phii); hi[4] = (f16)(r1.x * phii + q1.x * phr);
        hr[5] = (f16)(r1.y * phr - q1.y * phii); hi[5] = (f16)(r1.y * phii + q1.y * phr);
        hr[6] = (f16)(r1.z * phr - q1.z * phii); hi[6] = (f16)(r1.z * phii + q1.z * phr);
        hr[7] = (f16)(r1.w * phr - q1.w * phii); hi[7] = (f16)(r1.w * phii + q1.w * phr);
        *(float4*)(Rphr + (size_t)l * 4096 + base) = *(float4*)hr;
        *(float4*)(Rphi + (size_t)l * 4096 + base) = *(float4*)hi;
    }
}

__device__ __forceinline__ void convert_body(char* smem, int t, int pt, int tid,
        const float* __restrict__ x, f16* __restrict__ xh) {
    float (*Ls)[68] = (float(*)[68])smem;
    int p0 = pt * 64;
    const float* xb = x + (size_t)t * (NPHI * 64);
    #pragma unroll
    for (int e = 0; e < 4; ++e) {
        int idx = tid + e * 256;
        int row = idx >> 4, c4 = (idx & 15) * 4;
        int p = p0 + row;
        float4 v = make_float4(0.f, 0.f, 0.f, 0.f);
        if (p < NPHI) v = *(const float4*)(xb + (size_t)p * 64 + c4);
        *(float4*)&Ls[row][c4] = v;
    }
    __syncthreads();
    #pragma unroll
    for (int e = 0; e < 2; ++e) {
        int idx = tid + e * 256;
        int c = idx >> 3, r8 = (idx & 7) * 8;
        __align__(16) f16 tmp[8];
        #pragma unroll
        for (int j = 0; j < 8; ++j) tmp[j] = (f16)Ls[r8 + j][c];
        *(float4*)(xh + (size_t)t * 32768 + (size_t)c * 512 + p0 + r8) = *(float4*)tmp;
    }
}

__global__ __launch_bounds__(256) void k_setup(
        f16* __restrict__ legh, f16* __restrict__ leghT, double* __restrict__ w64,
        f16* __restrict__ CS, f16* __restrict__ A5,
        const float* __restrict__ Rr, const float* __restrict__ Ri,
        const float* __restrict__ Ar, const float* __restrict__ Ai, const float* __restrict__ te,
        f16* __restrict__ Rphr, f16* __restrict__ Rphi,
        const float* __restrict__ x, f16* __restrict__ xh) {
    __shared__ __align__(16) char smem[64 * 68 * 4];
    int bid = blockIdx.x, tid = threadIdx.x;
    if (bid < 128) {
        leg_body(smem, bid, tid, legh, leghT, w64);
    } else if (bid < 1152) {
        tables_body((bid - 128) * 256 + tid, CS, A5);
    } else if (bid < 1280) {
        prepR_body(smem, bid - 1152, tid, Rr, Ri, Ar, Ai, te, Rphr, Rphi);
    } else {
        int cb = bid - 1280;
        convert_body(smem, cb >> 3, cb & 7, tid, x, xh);
    }
}

// ==================== K_g1: stage 1 MFMA (unchanged round-4 form) ===========
__global__ __launch_bounds__(256) void k_g1(const f16* __restrict__ xh, const f16* __restrict__ cF,
        const f16* __restrict__ sF, const double* __restrict__ w64,
        f16* __restrict__ FwR, f16* __restrict__ FwI) {
    __shared__ f16 Ac[64][40], An[64][40], Bs[64][40];
    int t = blockIdx.x, mt = blockIdx.y, tid = threadIdx.x;
    const f16* A0 = cF + (size_t)(mt * 64) * 512;
    const f16* A1 = sF + (size_t)(mt * 64) * 512;
    const f16* B  = xh + (size_t)t * (64 * 512);
    f32x4 acc[2][2][2];
    #pragma unroll
    for (int a = 0; a < 2; ++a)
        #pragma unroll
        for (int b = 0; b < 2; ++b)
            #pragma unroll
            for (int c = 0; c < 2; ++c) acc[a][b][c] = (f32x4){0.f, 0.f, 0.f, 0.f};
    int lane = tid & 63, wid = tid >> 6;
    int wm = wid & 1, wn = wid >> 1;
    int fr = lane & 15, g8 = (lane >> 4) * 8;
    int row = tid >> 2, k8 = (tid & 3) * 8;
    for (int kt = 0; kt < 16; ++kt) {
        float4 va = *(const float4*)(A0 + (size_t)row * 512 + kt * 32 + k8);
        float4 vn = *(const float4*)(A1 + (size_t)row * 512 + kt * 32 + k8);
        float4 vb = *(const float4*)(B  + (size_t)row * 512 + kt * 32 + k8);
        __syncthreads();
        *(float4*)&Ac[row][k8] = va;
        *(float4*)&An[row][k8] = vn;
        *(float4*)&Bs[row][k8] = vb;
        __syncthreads();
        f16x8 b0 = *(f16x8*)&Bs[wn * 32 + fr][g8];
        f16x8 b1 = *(f16x8*)&Bs[wn * 32 + 16 + fr][g8];
        f16x8 a0 = *(f16x8*)&Ac[wm * 32 + fr][g8];
        f16x8 a1 = *(f16x8*)&Ac[wm * 32 + 16 + fr][g8];
        f16x8 s0 = *(f16x8*)&An[wm * 32 + fr][g8];
        f16x8 s1 = *(f16x8*)&An[wm * 32 + 16 + fr][g8];
        acc[0][0][0] = __builtin_amdgcn_mfma_f32_16x16x32_f16(a0, b0, acc[0][0][0], 0, 0, 0);
        acc[0][0][1] = __builtin_amdgcn_mfma_f32_16x16x32_f16(a0, b1, acc[0][0][1], 0, 0, 0);
        acc[0][1][0] = __builtin_amdgcn_mfma_f32_16x16x32_f16(a1, b0, acc[0][1][0], 0, 0, 0);
        acc[0][1][1] = __builtin_amdgcn_mfma_f32_16x16x32_f16(a1, b1, acc[0][1][1], 0, 0, 0);
        acc[1][0][0] = __builtin_amdgcn_mfma_f32_16x16x32_f16(s0, b0, acc[1][0][0], 0, 0, 0);
        acc[1][0][1] = __builtin_amdgcn_mfma_f32_16x16x32_f16(s0, b1, acc[1][0][1], 0, 0, 0);
        acc[1][1][0] = __builtin_amdgcn_mfma_f32_16x16x32_f16(s1, b0, acc[1][1][0], 0, 0, 0);
        acc[1][1][1] = __builtin_amdgcn_mfma_f32_16x16x32_f16(s1, b1, acc[1][1][1], 0, 0, 0);
    }
    float wf = (float)w64[t];
    int rg = (lane >> 4) * 4;
    #pragma unroll
    for (int mf = 0; mf < 2; ++mf)
        #pragma unroll
        for (int nf = 0; nf < 2; ++nf) {
            int c = wn * 32 + nf * 16 + fr;
            #pragma unroll
            for (int r = 0; r < 4; ++r) {
                int m = mt * 64 + wm * 32 + mf * 16 + rg + r;
                FwR[((size_t)m * 256 + t) * 64 + c] = (f16)(acc[0][mf][nf][r] * wf);
                FwI[((size_t)m * 256 + t) * 64 + c] = (f16)(acc[1][mf][nf][r] * wf);
            }
        }
}

// ==================== K_g2: B [t][c]; transpose at staging (b128 frag reads) =
__global__ __launch_bounds__(256) void k_g2(const f16* __restrict__ legh, const f16* __restrict__ FwR,
        const f16* __restrict__ FwI, f16* __restrict__ Xhr, f16* __restrict__ Xhi) {
    __shared__ f16 As[64][40];
    __shared__ f16 Brs[64][40], Bis[64][40];   // [c][k32]
    int m = blockIdx.x, lt = blockIdx.y, tid = threadIdx.x;
    const f16* A  = legh + (size_t)m * (128 * 256) + (size_t)(lt * 64) * 256;
    const f16* B0 = FwR + (size_t)m * 16384;   // [t][c]
    const f16* B1 = FwI + (size_t)m * 16384;
    f32x4 acc[2][2][2];
    #pragma unroll
    for (int a = 0; a < 2; ++a)
        #pragma unroll
        for (int b = 0; b < 2; ++b)
            #pragma unroll
            for (int c = 0; c < 2; ++c) acc[a][b][c] = (f32x4){0.f, 0.f, 0.f, 0.f};
    int lane = tid & 63, wid = tid >> 6;
    int wm = wid & 1, wn = wid >> 1;
    int fr = lane & 15, g8 = (lane >> 4) * 8;
    int row = tid >> 2, k8 = (tid & 3) * 8;
    int bc = tid & 63, bko = (tid >> 6) * 8;   // c, k-octet
    for (int kt = 0; kt < 8; ++kt) {
        float4 va = *(const float4*)(A + (size_t)row * 256 + kt * 32 + k8);
        __align__(16) f16 tr[8], ti[8];
        #pragma unroll
        for (int j = 0; j < 8; ++j) {
            size_t gi = (size_t)(kt * 32 + bko + j) * 64 + bc;
            tr[j] = B0[gi];
            ti[j] = B1[gi];
        }
        __syncthreads();
        *(float4*)&As[row][k8] = va;
        *(float4*)&Brs[bc][bko] = *(float4*)tr;
        *(float4*)&Bis[bc][bko] = *(float4*)ti;
        __syncthreads();
        f16x8 a0 = *(f16x8*)&As[wm * 32 + fr][g8];
        f16x8 a1 = *(f16x8*)&As[wm * 32 + 16 + fr][g8];
        f16x8 r0 = *(f16x8*)&Brs[wn * 32 + fr][g8];
        f16x8 r1 = *(f16x8*)&Brs[wn * 32 + 16 + fr][g8];
        f16x8 i0 = *(f16x8*)&Bis[wn * 32 + fr][g8];
        f16x8 i1 = *(f16x8*)&Bis[wn * 32 + 16 + fr][g8];
        acc[0][0][0] = __builtin_amdgcn_mfma_f32_16x16x32_f16(a0, r0, acc[0][0][0], 0, 0, 0);
        acc[0][0][1] = __builtin_amdgcn_mfma_f32_16x16x32_f16(a0, r1, acc[0][0][1], 0, 0, 0);
        acc[0][1][0] = __builtin_amdgcn_mfma_f32_16x16x32_f16(a1, r0, acc[0][1][0], 0, 0, 0);
        acc[0][1][1] = __builtin_amdgcn_mfma_f32_16x16x32_f16(a1, r1, acc[0][1][1], 0, 0, 0);
        acc[1][0][0] = __builtin_amdgcn_mfma_f32_16x16x32_f16(a0, i0, acc[1][0][0], 0, 0, 0);
        acc[1][0][1] = __builtin_amdgcn_mfma_f32_16x16x32_f16(a0, i1, acc[1][0][1], 0, 0, 0);
        acc[1][1][0] = __builtin_amdgcn_mfma_f32_16x16x32_f16(a1, i0, acc[1][1][0], 0, 0, 0);
        acc[1][1][1] = __builtin_amdgcn_mfma_f32_16x16x32_f16(a1, i1, acc[1][1][1], 0, 0, 0);
    }
    int rg = (lane >> 4) * 4;
    #pragma unroll
    for (int mf = 0; mf < 2; ++mf)
        #pragma unroll
        for (int nf = 0; nf < 2; ++nf) {
            int c = wn * 32 + nf * 16 + fr;
            #pragma unroll
            for (int r = 0; r < 4; ++r) {
                int l = lt * 64 + wm * 32 + mf * 16 + rg + r;
                Xhr[(size_t)m * 8192 + l * 64 + c] = (f16)acc[0][mf][nf][r];
                Xhi[(size_t)m * 8192 + l * 64 + c] = (f16)acc[1][mf][nf][r];
            }
        }
}

// ==================== K_s3m: stage 3 MFMA (unchanged) =======================
__global__ __launch_bounds__(256) void k_s3m(const f16* __restrict__ Xhr, const f16* __restrict__ Xhi,
        const f16* __restrict__ Rphr, const f16* __restrict__ Rphi,
        f16* __restrict__ Or, f16* __restrict__ Oi) {
    __shared__ f16 Ars[64][72], Ais[64][72], Ans[64][72];
    int l = blockIdx.x, mt = blockIdx.y, tid = threadIdx.x;
    {
        int arow = tid >> 2;
        int mp = mt * 64 + arow;
        int mmv = mp - 127, am = mmv < 0 ? -mmv : mmv;
        unsigned short cj = (mmv < 0) ? 0x8000 : 0;
        u16x8 cjv = {cj, cj, cj, cj, cj, cj, cj, cj};
        u16x8 ngv = {0x8000, 0x8000, 0x8000, 0x8000, 0x8000, 0x8000, 0x8000, 0x8000};
        #pragma unroll
        for (int e = 0; e < 2; ++e) {
            int ci8 = (tid & 3) * 8 + e * 32;
            u16x8 vr = {0, 0, 0, 0, 0, 0, 0, 0};
            u16x8 vi = {0, 0, 0, 0, 0, 0, 0, 0};
            if (mp < 255) {
                vr = *(const u16x8*)(Xhr + (size_t)am * 8192 + l * 64 + ci8);
                vi = *(const u16x8*)(Xhi + (size_t)am * 8192 + l * 64 + ci8);
            }
            u16x8 vic = vi ^ cjv;
            u16x8 vin = vic ^ ngv;
            *(u16x8*)&Ars[arow][ci8] = vr;
            *(u16x8*)&Ais[arow][ci8] = vic;
            *(u16x8*)&Ans[arow][ci8] = vin;
        }
    }
    __syncthreads();
    int lane = tid & 63, wid = tid >> 6;
    int wm = wid & 1, wn = wid >> 1;
    int fr = lane & 15, g8 = (lane >> 4) * 8;
    const f16* Bre = Rphr + (size_t)l * 4096;
    const f16* Bim = Rphi + (size_t)l * 4096;
    f32x4 accr[2][2], acci[2][2];
    #pragma unroll
    for (int a = 0; a < 2; ++a)
        #pragma unroll
        for (int b = 0; b < 2; ++b) { accr[a][b] = (f32x4){0.f,0.f,0.f,0.f}; acci[a][b] = (f32x4){0.f,0.f,0.f,0.f}; }
    #pragma unroll
    for (int ks = 0; ks < 2; ++ks) {
        int ko = ks * 32 + g8;
        f16x8 ar0 = *(f16x8*)&Ars[wm * 32 + fr][ko];
        f16x8 ar1 = *(f16x8*)&Ars[wm * 32 + 16 + fr][ko];
        f16x8 ai0 = *(f16x8*)&Ais[wm * 32 + fr][ko];
        f16x8 ai1 = *(f16x8*)&Ais[wm * 32 + 16 + fr][ko];
        f16x8 an0 = *(f16x8*)&Ans[wm * 32 + fr][ko];
        f16x8 an1 = *(f16x8*)&Ans[wm * 32 + 16 + fr][ko];
        #pragma unroll
        for (int nf = 0; nf < 2; ++nf) {
            int brow = wn * 32 + nf * 16 + fr;
            f16x8 br = *(const f16x8*)(Bre + (size_t)brow * 64 + ko);
            f16x8 bi = *(const f16x8*)(Bim + (size_t)brow * 64 + ko);
            accr[0][nf] = __builtin_amdgcn_mfma_f32_16x16x32_f16(ar0, br, accr[0][nf], 0, 0, 0);
            accr[0][nf] = __builtin_amdgcn_mfma_f32_16x16x32_f16(an0, bi, accr[0][nf], 0, 0, 0);
            acci[0][nf] = __builtin_amdgcn_mfma_f32_16x16x32_f16(ar0, bi, acci[0][nf], 0, 0, 0);
            acci[0][nf] = __builtin_amdgcn_mfma_f32_16x16x32_f16(ai0, br, acci[0][nf], 0, 0, 0);
            accr[1][nf] = __builtin_amdgcn_mfma_f32_16x16x32_f16(ar1, br, accr[1][nf], 0, 0, 0);
            accr[1][nf] = __builtin_amdgcn_mfma_f32_16x16x32_f16(an1, bi, accr[1][nf], 0, 0, 0);
            acci[1][nf] = __builtin_amdgcn_mfma_f32_16x16x32_f16(ar1, bi, acci[1][nf], 0, 0, 0);
            acci[1][nf] = __builtin_amdgcn_mfma_f32_16x16x32_f16(ai1, br, acci[1][nf], 0, 0, 0);
        }
    }
    int rg = (lane >> 4) * 4;
    #pragma unroll
    for (int mf = 0; mf < 2; ++mf)
        #pragma unroll
        for (int nf = 0; nf < 2; ++nf) {
            int co = wn * 32 + nf * 16 + fr;
            #pragma unroll
            for (int r = 0; r < 4; ++r) {
                int mp = mt * 64 + wm * 32 + mf * 16 + rg + r;
                if (mp < 255) {
                    Or[(size_t)mp * 8192 + l * 64 + co] = (f16)accr[mf][nf][r];
                    Oi[(size_t)mp * 8192 + l * 64 + co] = (f16)acci[mf][nf][r];
                }
            }
        }
}

// ==================== K_g4: B [l][c]; transpose at staging ===================
__global__ __launch_bounds__(256) void k_g4(const f16* __restrict__ legT, const f16* __restrict__ Or,
        const f16* __restrict__ Oi, f16* __restrict__ G) {
    __shared__ f16 As[64][40];
    __shared__ f16 Brs[64][40], Bis[64][40];   // [c][k32]
    int mp = blockIdx.x, tt = blockIdx.y, tid = threadIdx.x;
    int mmv = mp - 127, am = mmv < 0 ? -mmv : mmv;
    const f16* A  = legT + (size_t)am * (256 * 128) + (size_t)(tt * 64) * 128;
    const f16* B0 = Or + (size_t)mp * 8192;   // [l][c]
    const f16* B1 = Oi + (size_t)mp * 8192;
    f32x4 acc[2][2][2];
    #pragma unroll
    for (int a = 0; a < 2; ++a)
        #pragma unroll
        for (int b = 0; b < 2; ++b)
            #pragma unroll
            for (int c = 0; c < 2; ++c) acc[a][b][c] = (f32x4){0.f, 0.f, 0.f, 0.f};
    int lane = tid & 63, wid = tid >> 6;
    int wm = wid & 1, wn = wid >> 1;
    int fr = lane & 15, g8 = (lane >> 4) * 8;
    int row = tid >> 2, k8 = (tid & 3) * 8;
    int bc = tid & 63, bko = (tid >> 6) * 8;
    for (int kt = am >> 5; kt < 4; ++kt) {
        float4 va = *(const float4*)(A + (size_t)row * 128 + kt * 32 + k8);
        __align__(16) f16 tr[8], ti[8];
        #pragma unroll
        for (int j = 0; j < 8; ++j) {
            size_t gi = (size_t)(kt * 32 + bko + j) * 64 + bc;
            tr[j] = B0[gi];
            ti[j] = B1[gi];
        }
        __syncthreads();
        *(float4*)&As[row][k8] = va;
        *(float4*)&Brs[bc][bko] = *(float4*)tr;
        *(float4*)&Bis[bc][bko] = *(float4*)ti;
        __syncthreads();
        f16x8 a0 = *(f16x8*)&As[wm * 32 + fr][g8];
        f16x8 a1 = *(f16x8*)&As[wm * 32 + 16 + fr][g8];
        f16x8 r0 = *(f16x8*)&Brs[wn * 32 + fr][g8];
        f16x8 r1 = *(f16x8*)&Brs[wn * 32 + 16 + fr][g8];
        f16x8 i0 = *(f16x8*)&Bis[wn * 32 + fr][g8];
        f16x8 i1 = *(f16x8*)&Bis[wn * 32 + 16 + fr][g8];
        acc[0][0][0] = __builtin_amdgcn_mfma_f32_16x16x32_f16(a0, r0, acc[0][0][0], 0, 0, 0);
        acc[0][0][1] = __builtin_amdgcn_mfma_f32_16x16x32_f16(a0, r1, acc[0][0][1], 0, 0, 0);
        acc[0][1][0] = __builtin_amdgcn_mfma_f32_16x16x32_f16(a1, r0, acc[0][1][0], 0, 0, 0);
        acc[0][1][1] = __builtin_amdgcn_mfma_f32_16x16x32_f16(a1, r1, acc[0][1][1], 0, 0, 0);
        acc[1][0][0] = __builtin_amdgcn_mfma_f32_16x16x32_f16(a0, i0, acc[1][0][0], 0, 0, 0);
        acc[1][0][1] = __builtin_amdgcn_mfma_f32_16x16x32_f16(a0, i1, acc[1][0][1], 0, 0, 0);
        acc[1][1][0] = __builtin_amdgcn_mfma_f32_16x16x32_f16(a1, i0, acc[1][1][0], 0, 0, 0);
        acc[1][1][1] = __builtin_amdgcn_mfma_f32_16x16x32_f16(a1, i1, acc[1][1][1], 0, 0, 0);
    }
    int rg = (lane >> 4) * 4;
    f16* gr = G + (size_t)(2 * mp) * (256 * 64);
    f16* gi = G + (size_t)(2 * mp + 1) * (256 * 64);
    #pragma unroll
    for (int mf = 0; mf < 2; ++mf)
        #pragma unroll
        for (int nf = 0; nf < 2; ++nf) {
            int c = wn * 32 + nf * 16 + fr;
            #pragma unroll
            for (int r = 0; r < 4; ++r) {
                int tl = tt * 64 + wm * 32 + mf * 16 + rg + r;
                gr[(size_t)tl * 64 + c] = (f16)acc[0][mf][nf][r];
                gi[(size_t)tl * 64 + c] = (f16)acc[1][mf][nf][r];
            }
        }
}

// ==================== K_g5: B [k][t][c]; transpose at staging ================
__global__ __launch_bounds__(256) void k_g5(const f16* __restrict__ A5, const f16* __restrict__ Gk,
                                            float* __restrict__ out) {
    __shared__ f16 As[64][40];
    __shared__ f16 Bs2[64][40];   // [c][k32]
    int t = blockIdx.x, pt = blockIdx.y, tid = threadIdx.x;
    const f16* A = A5 + (size_t)(pt * 64) * 512;
    f32x4 acc[2][2];
    #pragma unroll
    for (int a = 0; a < 2; ++a)
        #pragma unroll
        for (int b = 0; b < 2; ++b) acc[a][b] = (f32x4){0.f, 0.f, 0.f, 0.f};
    int lane = tid & 63, wid = tid >> 6;
    int wm = wid & 1, wn = wid >> 1;
    int fr = lane & 15, g8 = (lane >> 4) * 8;
    int row = tid >> 2, k8 = (tid & 3) * 8;
    int bc = tid & 63, bko = (tid >> 6) * 8;
    for (int kt = 0; kt < 16; ++kt) {
        float4 va = *(const float4*)(A + (size_t)row * 512 + kt * 32 + k8);
        __align__(16) f16 tb[8];
        #pragma unroll
        for (int j = 0; j < 8; ++j)
            tb[j] = Gk[(size_t)(kt * 32 + bko + j) * 16384 + t * 64 + bc];
        __syncthreads();
        *(float4*)&As[row][k8] = va;
        *(float4*)&Bs2[bc][bko] = *(float4*)tb;
        __syncthreads();
        f16x8 a0 = *(f16x8*)&As[wm * 32 + fr][g8];
        f16x8 a1 = *(f16x8*)&As[wm * 32 + 16 + fr][g8];
        f16x8 b0 = *(f16x8*)&Bs2[wn * 32 + fr][g8];
        f16x8 b1 = *(f16x8*)&Bs2[wn * 32 + 16 + fr][g8];
        acc[0][0] = __builtin_amdgcn_mfma_f32_16x16x32_f16(a0, b0, acc[0][0], 0, 0, 0);
        acc[0][1] = __builtin_amdgcn_mfma_f32_16x16x32_f16(a0, b1, acc[0][1], 0, 0, 0);
        acc[1][0] = __builtin_amdgcn_mfma_f32_16x16x32_f16(a1, b0, acc[1][0], 0, 0, 0);
        acc[1][1] = __builtin_amdgcn_mfma_f32_16x16x32_f16(a1, b1, acc[1][1], 0, 0, 0);
    }
    int rg = (lane >> 4) * 4;
    #pragma unroll
    for (int mf = 0; mf < 2; ++mf)
        #pragma unroll
        for (int nf = 0; nf < 2; ++nf) {
            int c = wn * 32 + nf * 16 + fr;
            #pragma unroll
            for (int r = 0; r < 4; ++r) {
                int p = pt * 64 + wm * 32 + mf * 16 + rg + r;
                if (p < NPHI) out[((size_t)t * NPHI + p) * 64 + c] = acc[mf][nf][r];
            }
        }
}

extern "C" void kernel_launch(void* const* d_in, const int* in_sizes, int n_in,
                              void* d_out, int out_size, void* d_ws, size_t ws_size,
                              hipStream_t stream) {
    const float* x    = (const float*)d_in[0];
    const float* temb = (const float*)d_in[1];
    const float* Ar   = (const float*)d_in[2];
    const float* Ai   = (const float*)d_in[3];
    const float* Rr   = (const float*)d_in[4];
    const float* Ri   = (const float*)d_in[5];
    float* out = (float*)d_out;

    char* ws = (char*)d_ws;
    size_t off = 0;
    auto alloc = [&](size_t bytes) -> void* {
        void* p = ws + off;
        off = (off + bytes + 255) & ~(size_t)255;
        return p;
    };
    double* w64  = (double*)alloc(256 * 8);
    f16* legh   = (f16*)alloc((size_t)128 * 128 * 256 * 2);   // 8.39 MB
    f16* leghT  = (f16*)alloc((size_t)128 * 256 * 128 * 2);   // 8.39 MB
    f16* CS     = (f16*)alloc((size_t)2 * 128 * 512 * 2);     // 256 KB
    f16* A5     = (f16*)alloc((size_t)512 * 512 * 2);         // 512 KB
    f16* Rphr   = (f16*)alloc((size_t)128 * 64 * 64 * 2);     // 1.05 MB
    f16* Rphi   = (f16*)alloc((size_t)128 * 64 * 64 * 2);
    f16* R1     = (f16*)alloc((size_t)256 * 64 * 512 * 2);    // 16.78 MB: xh -> Or/Oi
    f16* R2     = (f16*)alloc((size_t)512 * 256 * 64 * 2);    // 16.78 MB: FwR/FwI/Xh -> Gk
    if (off > ws_size) return;

    f16* xh  = R1;                          // dead after k_g1
    f16* Or  = R1;                          // written by k_s3m
    f16* Oi  = R1 + (size_t)2097152;
    f16* FwR = R2;                          // written by k_g1, read by k_g2
    f16* FwI = R2 + (size_t)2097152;
    f16* Xhr = R2 + (size_t)4194304;        // written by k_g2 (does not alias Fw)
    f16* Xhi = R2 + (size_t)6291456;
    f16* Gk  = R2;                          // k_g4 output; rows 510,511 stale-but-finite, A5 cols 510,511 == 0
    f16* cF  = CS;
    f16* sF  = CS + (size_t)65536;

    hipLaunchKernelGGL(k_setup, dim3(3328),     dim3(256), 0, stream,
                       legh, leghT, w64, CS, A5, Rr, Ri, Ar, Ai, temb, Rphr, Rphi, x, xh);
    hipLaunchKernelGGL(k_g1,    dim3(256, 2),   dim3(256), 0, stream, xh, cF, sF, w64, FwR, FwI);
    hipLaunchKernelGGL(k_g2,    dim3(128, 2),   dim3(256), 0, stream, legh, FwR, FwI, Xhr, Xhi);
    hipLaunchKernelGGL(k_s3m,   dim3(128, 4),   dim3(256), 0, stream, Xhr, Xhi, Rphr, Rphi, Or, Oi);
    hipLaunchKernelGGL(k_g4,    dim3(255, 4),   dim3(256), 0, stream, leghT, Or, Oi, Gk);
    hipLaunchKernelGGL(k_g5,    dim3(256, 8),   dim3(256), 0, stream, A5, Gk, out);
}